// Round 13
// baseline (258.057 us; speedup 1.0000x reference)
//
#include <hip/hip_runtime.h>
#include <math.h>

// Problem constants
#define LL   4096      // H*W
#define DI   128       // 2*C
#define CC   64        // C
#define BB   8         // batch
#define KK   4         // scan directions
#define LB   32768     // pixels per instance
#define NPIX 2097152   // B*H*W*C elements of s
#define EPSF 1e-5f
#define LOG2E 1.44269504089f
#define LN2F  0.69314718056f

// Workspace layout (float-indexed offsets; most regions hold bf16).
#define OFF_XCIN   ((size_t)0)
#define OFF_XCONV  ((size_t)4194304)
#define OFF_XCONVT ((size_t)8388608)
#define OFF_Z      ((size_t)12582912)
#define OFF_Y      ((size_t)16777216)
#define OFF_YT     ((size_t)20971520)
#define OFF_XDBL   ((size_t)25165824)   // bf16: 786432 shorts (lower half of region)
#define ISTRIDE    ((size_t)25952256)   // floats per instance
// Aliases (lifetime-disjoint reuse):
#define OFF_YCOMBT OFF_XCIN             // xcin dead after k2; ycombT (d-major) by k3b
#define OFF_XNEW   OFF_YT               // xnew (pixel-major bf16) by k4a
// bf16 weight block: dead upper part of the OFF_Y region.
#define OFF_WB     (OFF_Y + (size_t)2097152)
// short-offsets inside the weight block:
#define WB_IPW 0        // [256][64]
#define WB_OPW 16384    // [64][128]
#define WB_F1W 24576    // [256][64]
#define WB_F2W 40960    // [64][256]
#define WB_TOT 57344

typedef short v8s __attribute__((ext_vector_type(8)));
typedef float v4f __attribute__((ext_vector_type(4)));

__device__ __forceinline__ float fexp_(float x){ return __expf(x); }
__device__ __forceinline__ float silu_(float x){ return __fdividef(x, 1.f+__expf(-x)); }
__device__ __forceinline__ float geluf_(float x){ return 0.5f*x*(1.f+erff(x*0.70710678118f)); }
__device__ __forceinline__ short bf16_(float x){
  unsigned u = __float_as_uint(x);
  u += 0x7FFF + ((u>>16)&1);     // RNE
  return (short)(u>>16);
}
__device__ __forceinline__ float bf2f_(short s){
  return __uint_as_float(((unsigned)(unsigned short)s)<<16);
}

#define LD16(dst, ptr) { const float4* p4_=(const float4*)(ptr);                 \
  float4 v0_=p4_[0], v1_=p4_[1], v2_=p4_[2], v3_=p4_[3];                         \
  dst[0]=v0_.x; dst[1]=v0_.y; dst[2]=v0_.z; dst[3]=v0_.w;                        \
  dst[4]=v1_.x; dst[5]=v1_.y; dst[6]=v1_.z; dst[7]=v1_.w;                        \
  dst[8]=v2_.x; dst[9]=v2_.y; dst[10]=v2_.z; dst[11]=v2_.w;                      \
  dst[12]=v3_.x; dst[13]=v3_.y; dst[14]=v3_.z; dst[15]=v3_.w; }
// 16 bf16 (32B) -> 16 floats
#define LD16H(dst, ptr) { const v8s* p8_=(const v8s*)(ptr);                      \
  v8s a0_=p8_[0], a1_=p8_[1];                                                    \
  _Pragma("unroll") for(int e_=0;e_<8;++e_){ dst[e_]=bf2f_(a0_[e_]);             \
                                             dst[8+e_]=bf2f_(a1_[e_]); } }
// 8 bf16 (16B) -> 8 floats
#define LD8H(dst, ptr) { const v8s a0_ = *(const v8s*)(ptr);                     \
  _Pragma("unroll") for(int e_=0;e_<8;++e_) dst[e_]=bf2f_(a0_[e_]); }
// 8 bf16 reversed: dst[7-m] = ptr[m]
#define LD8HR(dst, ptr) { const v8s a0_ = *(const v8s*)(ptr);                    \
  _Pragma("unroll") for(int e_=0;e_<8;++e_) dst[7-e_]=bf2f_(a0_[e_]); }
// 16 floats -> 16 bf16 (2 v8s stores)
#define ST16H(ptr, srcv) { v8s o0_, o1_;                                         \
  _Pragma("unroll") for(int e_=0;e_<8;++e_){ o0_[e_]=bf16_(srcv[e_]);            \
                                             o1_[e_]=bf16_(srcv[8+e_]); }        \
  ((v8s*)(ptr))[0]=o0_; ((v8s*)(ptr))[1]=o1_; }
// 8 floats -> 8 bf16
#define ST8H(ptr, srcv) { v8s o0_;                                               \
  _Pragma("unroll") for(int e_=0;e_<8;++e_) o0_[e_]=bf16_(srcv[e_]);             \
  *((v8s*)(ptr))=o0_; }

// KW: one-shot f32 -> bf16 conversion of all MFMA weight matrices into ws.
__global__ __launch_bounds__(256) void kw_prep(
    const float* __restrict__ ipw_, const float* __restrict__ opw_,
    const float* __restrict__ f1w_, const float* __restrict__ f2w_,
    float* __restrict__ ws)
{
  const int i = blockIdx.y;
  short* wb = (short*)(ws + (size_t)i*ISTRIDE + OFF_WB);
  const int e0 = blockIdx.x*1024 + threadIdx.x;
  #pragma unroll
  for(int k=0;k<4;++k){
    const int e = e0 + k*256;
    float v;
    if(e < WB_OPW)      v = ipw_[(size_t)i*16384 + e];
    else if(e < WB_F1W) v = opw_[(size_t)i*8192  + (e - WB_OPW)];
    else if(e < WB_F2W) v = f1w_[(size_t)i*16384 + (e - WB_F1W)];
    else                v = f2w_[(size_t)i*16384 + (e - WB_F2W)];
    wb[e] = bf16_(v);
  }
}

// K1 (MFMA): block = 64 pixels, 4 waves; LN -> bf16 hlds; ipw staged per half
// from pre-converted bf16 weights; outputs xcin (bf16, b,d,l) and zT (bf16,
// d-major silu).
__global__ __launch_bounds__(256) void k1_ln_inproj(
    const float* __restrict__ xmag, const float* __restrict__ xph,
    const float* __restrict__ n1w_, const float* __restrict__ n1b_,
    float* __restrict__ ws)
{
  const int i = blockIdx.y;
  const float* xin = i ? xph : xmag;
  const float* n1w = n1w_ + i*CC;
  const float* n1b = n1b_ + i*CC;
  float* base = ws + (size_t)i*ISTRIDE;
  const short* wb_ipw = (const short*)(base + OFF_WB) + WB_IPW;
  const int t = threadIdx.x, lane = t & 63;
  const int wv = __builtin_amdgcn_readfirstlane(t >> 6);
  const int m = lane & 15, quad = lane >> 4;
  const int p0 = blockIdx.x*64;
  const int b = p0 >> 12, l0 = p0 & (LL-1);

  __shared__ short hlds[64*72];
  __shared__ short w1lds[128*72];
  __shared__ float outs[128*68];

  {
    float hn[CC];
    const float* xr = xin + (size_t)(p0 + lane)*CC;
    LD16(hn, xr); LD16((hn+16), xr+16); LD16((hn+32), xr+32); LD16((hn+48), xr+48);
    float s1=0.f, s2=0.f;
    #pragma unroll
    for(int c=0;c<CC;++c){ s1 += hn[c]; s2 += hn[c]*hn[c]; }
    const float mu = s1*(1.f/CC);
    const float rs = rsqrtf(s2*(1.f/CC) - mu*mu + EPSF);
    if(wv==0){
      #pragma unroll
      for(int q=0;q<8;++q){
        v8s s;
        #pragma unroll
        for(int e=0;e<8;++e){
          const int c = q*8+e;
          s[e] = bf16_((hn[c]-mu)*rs*n1w[c] + n1b[c]);
        }
        *(v8s*)&hlds[lane*72 + q*8] = s;
      }
    }
  }

  for(int h=0; h<2; ++h){
    if(h) __syncthreads();
    {
      const int jl = t >> 1, hc = (t & 1)*32;
      const short* src = wb_ipw + (size_t)(h*128 + jl)*64 + hc;
      #pragma unroll
      for(int q=0;q<4;++q)
        *(v8s*)&w1lds[jl*72 + hc + q*8] = ((const v8s*)src)[q];
    }
    __syncthreads();
    #pragma unroll 2
    for(int nt=0; nt<8; ++nt){
      v4f acc = (v4f){0.f,0.f,0.f,0.f};
      #pragma unroll
      for(int ks=0; ks<2; ++ks){
        const v8s a = *(const v8s*)&hlds[(wv*16 + m)*72 + ks*32 + quad*8];
        const v8s bb = *(const v8s*)&w1lds[(nt*16 + m)*72 + ks*32 + quad*8];
        acc = __builtin_amdgcn_mfma_f32_16x16x32_bf16(a, bb, acc, 0, 0, 0);
      }
      *(float4*)&outs[(nt*16 + m)*68 + wv*16 + quad*4] =
          make_float4(acc[0], acc[1], acc[2], acc[3]);
    }
    __syncthreads();
    const int jl = t >> 1, hc = (t & 1)*32;
    if(h==0){
      short* xcb = (short*)(base + OFF_XCIN) + (size_t)b*DI*LL + (size_t)jl*LL + l0 + hc;
      const float* so = &outs[jl*68 + hc];
      ST16H(xcb, so);
      ST16H(xcb+16, (so+16));
    } else {
      short* zr = (short*)(base + OFF_Z) + (size_t)jl*LB + p0 + hc;
      float tmp[32];
      #pragma unroll
      for(int e=0;e<32;++e) tmp[e] = silu_(outs[jl*68 + hc + e]);
      ST16H(zr, tmp);
      ST16H(zr+16, (tmp+16));
    }
  }
}

// K2: depthwise 3x3 conv + silu; bf16 in (xcin), bf16 out (xconv/xconvT).
// v8s-vectorized input load into a zero-padded 66x66 fp32 tile -> branch-free
// 3x3 window (no bounds checks).
__global__ __launch_bounds__(256) void k2_dwconv(
    const float* __restrict__ cw_, float* __restrict__ ws)
{
  const int i = blockIdx.y;
  const int bd = blockIdx.x;
  const int d = bd & (DI-1);
  const float* cw = cw_ + i*DI*9 + d*9;
  const short* xcin = (const short*)(ws + (size_t)i*ISTRIDE + OFF_XCIN) + (size_t)bd*LL;
  short* xconv  = (short*)(ws + (size_t)i*ISTRIDE + OFF_XCONV ) + (size_t)bd*LL;
  short* xconvT = (short*)(ws + (size_t)i*ISTRIDE + OFF_XCONVT) + (size_t)bd*LL;
  __shared__ float tin[66*66];     // zero-padded border
  __shared__ float tout[64*65];
  const int t = threadIdx.x;
  float w9[9];
  #pragma unroll
  for(int q=0;q<9;++q) w9[q] = cw[q];
  // zero-fill (border matters; interior overwritten below after barrier)
  for(int idx=t; idx<66*66; idx+=256) tin[idx] = 0.f;
  __syncthreads();
  // vectorized interior fill: 2 x v8s per thread
  #pragma unroll
  for(int pass=0; pass<2; ++pass){
    const int e = t*8 + pass*2048;           // element index, 8-aligned
    const int row = e >> 6, col = e & 63;
    const v8s v = *(const v8s*)&xcin[e];
    #pragma unroll
    for(int q=0;q<8;++q)
      tin[(row+1)*66 + col+1 + q] = bf2f_(v[q]);
  }
  __syncthreads();
  const int w = t & 63, hb = (t>>6)*16;
  #pragma unroll
  for(int r=0;r<16;++r){
    const int h = hb + r;
    const float* tc = &tin[h*66 + w];        // (h-1+1)*66 + (w-1+1): window origin
    float acc = tc[0]*w9[0] + tc[1]*w9[1] + tc[2]*w9[2]
              + tc[66]*w9[3] + tc[67]*w9[4] + tc[68]*w9[5]
              + tc[132]*w9[6] + tc[133]*w9[7] + tc[134]*w9[8];
    const float o = silu_(acc);
    tout[h*65+w] = o;
    xconv[h*64+w] = bf16_(o);
  }
  __syncthreads();
  const int hcol = t & 63, wb = (t>>6)*16;
  #pragma unroll
  for(int r=0;r<16;++r){
    const int wp = wb + r;
    xconvT[wp*64 + hcol] = bf16_(tout[hcol*65 + wp]);
  }
}

// K3a: paired-direction x_proj from bf16 src; xdbl stored bf16.
__global__ __launch_bounds__(256) void k3a_xproj(
    const float* __restrict__ xpw_, float* __restrict__ ws)
{
  const int i = blockIdx.z;
  const int b = blockIdx.y >> 1;
  const int kp = blockIdx.y & 1;
  const int l = blockIdx.x*256 + threadIdx.x;   // source index
  const short* src = (const short*)(ws + (size_t)i*ISTRIDE + (kp? OFF_XCONVT : OFF_XCONV))
                     + (size_t)b*DI*LL;
  const float* xpwF = xpw_ + i*KK*6*DI + kp*6*DI;
  const float* xpwB = xpw_ + i*KK*6*DI + (kp+2)*6*DI;
  float accF[6] = {0,0,0,0,0,0};
  float accB[6] = {0,0,0,0,0,0};
  for(int d=0; d<DI; ++d){
    const float xv = bf2f_(src[(size_t)d*LL + l]);
    #pragma unroll
    for(int c=0;c<6;++c){
      accF[c] += xv * xpwF[c*DI + d];
      accB[c] += xv * xpwB[c*DI + d];
    }
  }
  short* xdF = (short*)(ws + (size_t)i*ISTRIDE + OFF_XDBL) + (size_t)(b*KK+kp  )*6*LL;
  short* xdB = (short*)(ws + (size_t)i*ISTRIDE + OFF_XDBL) + (size_t)(b*KK+kp+2)*6*LL;
  #pragma unroll
  for(int c=0;c<6;++c) xdF[(size_t)c*LL + l] = bf16_(accF[c]);
  #pragma unroll
  for(int c=0;c<6;++c) xdB[(size_t)c*LL + (LL-1-l)] = bf16_(accB[c]);
}

// K3b (merged): one block per (b,d); computes BOTH direction pairs (kp=0,1),
// combines y + transpose(yT) in an LDS fp32 tile, writes d-major bf16 ycombT.
// exp2-domain softplus; scan in t-units, ln2 folded at the C-multiply.
// GEOMETRY 512x8 (was 256x16): halves the serial fB=fB*a+b chain length and
// halves live arrays (40 floats) -> (512,2) = 16 waves/CU (50% occ, was 33%).
// Latency-bound kernel: more TLP + shorter chains. (256,6) is known-fatal
// (R6 spills); spill tripwire = WRITE_SIZE must stay 16.4MB.
__global__ __launch_bounds__(512,2) void k3b_scan(
    const float* __restrict__ dtw_, const float* __restrict__ dtb_,
    const float* __restrict__ alog_, const float* __restrict__ Ds_,
    float* __restrict__ ws)
{
  const int gid = blockIdx.x;           // b*128 + d
  const int i = blockIdx.y;
  const int d  = gid & (DI-1);
  const int b  = gid >> 7;
  const int t = threadIdx.x, lane = t & 63, wv = t >> 6;   // wv 0..7
  float* base = ws + (size_t)i*ISTRIDE;
  const int l0 = t*8;
  const int s0 = LL - 8 - l0;

  __shared__ float tile[64*65];
  __shared__ float wAg[8], wBg[8], vAg[8], vBg[8];

  #pragma unroll 1
  for(int kp=0; kp<2; ++kp){
    const short* src = (const short*)(base + (kp? OFF_XCONVT : OFF_XCONV)) + (size_t)(b*DI+d)*LL;
    const short* xdF = (const short*)(base + OFF_XDBL) + (size_t)(b*KK+kp  )*6*LL;
    const short* xdB = (const short*)(base + OFF_XDBL) + (size_t)(b*KK+kp+2)*6*LL;
    const int kdF = kp*DI + d, kdB = (kp+2)*DI + d;
    const float4 wF = ((const float4*)dtw_)[i*KK*DI + kdF];
    const float4 wB = ((const float4*)dtw_)[i*KK*DI + kdB];
    const float biasF = dtb_[i*KK*DI + kdF], biasB = dtb_[i*KK*DI + kdB];
    const float AvF = -fexp_(alog_[i*KK*DI + kdF]);
    const float AvB = -fexp_(alog_[i*KK*DI + kdB]);
    const float Dsum = Ds_[i*KK*DI + kdF] + Ds_[i*KK*DI + kdB];

    float vX[8], aF[8], bF[8], aB[8], bB[8];
    float fA = 1.f, fB = 0.f, gA = 1.f, gB = 0.f;
    LD8H(vX, src + l0);

    {
      float pre[8], r0[8];
      LD8H(r0, xdF + 0*LL + l0);
      #pragma unroll
      for(int j=0;j<8;++j) pre[j] = biasF + wF.x*r0[j];
      LD8H(r0, xdF + 1*LL + l0);
      #pragma unroll
      for(int j=0;j<8;++j) pre[j] += wF.y*r0[j];
      LD8H(r0, xdF + 2*LL + l0);
      #pragma unroll
      for(int j=0;j<8;++j) pre[j] += wF.z*r0[j];
      LD8H(r0, xdF + 3*LL + l0);
      #pragma unroll
      for(int j=0;j<8;++j) pre[j] += wF.w*r0[j];
      LD8H(r0, xdF + 4*LL + l0);   // Bs
      #pragma unroll
      for(int j=0;j<8;++j){
        const float tt = __builtin_log2f(1.f + __builtin_exp2f(pre[j]*LOG2E));
        aF[j] = __builtin_exp2f(AvF*tt);
        bF[j] = tt*r0[j]*vX[j];
        fB = fB*aF[j] + bF[j];
        fA *= aF[j];
      }
    }
    {
      float pre[8], r0[8];
      LD8HR(r0, xdB + 0*LL + s0);
      #pragma unroll
      for(int j=0;j<8;++j) pre[j] = biasB + wB.x*r0[j];
      LD8HR(r0, xdB + 1*LL + s0);
      #pragma unroll
      for(int j=0;j<8;++j) pre[j] += wB.y*r0[j];
      LD8HR(r0, xdB + 2*LL + s0);
      #pragma unroll
      for(int j=0;j<8;++j) pre[j] += wB.z*r0[j];
      LD8HR(r0, xdB + 3*LL + s0);
      #pragma unroll
      for(int j=0;j<8;++j) pre[j] += wB.w*r0[j];
      LD8HR(r0, xdB + 4*LL + s0);  // Bs reversed
      #pragma unroll
      for(int j=7;j>=0;--j){
        const float tt = __builtin_log2f(1.f + __builtin_exp2f(pre[j]*LOG2E));
        aB[j] = __builtin_exp2f(AvB*tt);
        bB[j] = tt*r0[j]*vX[j];
        gB = gB*aB[j] + bB[j];
        gA *= aB[j];
      }
    }

    #pragma unroll
    for(int off=1; off<64; off<<=1){
      const float aL = __shfl_up(fA, off);
      const float bL = __shfl_up(fB, off);
      if(lane >= off){ fB = bL*fA + fB; fA = aL*fA; }
    }
    float pA = __shfl_up(fA, 1), pB = __shfl_up(fB, 1);
    if(lane==0){ pA=1.f; pB=0.f; }
    #pragma unroll
    for(int off=1; off<64; off<<=1){
      const float aR = __shfl_down(gA, off);
      const float bR = __shfl_down(gB, off);
      if(lane + off < 64){ gB = gA*bR + gB; gA = gA*aR; }
    }
    float qA = __shfl_down(gA, 1), qB = __shfl_down(gB, 1);
    if(lane==63){ qA=1.f; qB=0.f; }

    if(kp) __syncthreads();
    if(lane==63){ wAg[wv]=fA; wBg[wv]=fB; }
    if(lane==0){ vAg[wv]=gA; vBg[wv]=gB; }
    __syncthreads();
    float eB=0.f;
    for(int u=0; u<wv; ++u){ eB = wAg[u]*eB + wBg[u]; }
    float rB=0.f;
    for(int u=7; u>wv; --u){ rB = vAg[u]*rB + vBg[u]; }

    float hf = pA*eB + pB;
    float hb = qA*rB + qB;

    float out[8], cc[8];
    LD8H(cc, xdF + 5*LL + l0);
    #pragma unroll
    for(int j=0;j<8;++j){
      hf = aF[j]*hf + bF[j];
      out[j] = hf*(cc[j]*LN2F) + Dsum*vX[j];   // ln2 fold (scan in t-units)
    }
    LD8HR(cc, xdB + 5*LL + s0);
    #pragma unroll
    for(int j=7;j>=0;--j){
      hb = aB[j]*hb + bB[j];
      out[j] += hb*(cc[j]*LN2F);
    }

    if(kp==0){
      #pragma unroll
      for(int j=0;j<8;++j){
        const int l = l0 + j;
        tile[(l>>6)*65 + (l&63)] = out[j];
      }
    } else {
      #pragma unroll
      for(int j=0;j<8;++j){
        const int q = l0 + j;
        tile[(q&63)*65 + (q>>6)] += out[j];
      }
    }
  }

  __syncthreads();
  {
    short* ycT = (short*)(base + OFF_YCOMBT);
    float o[8];
    #pragma unroll
    for(int j=0;j<8;++j)
      o[j] = tile[(t>>3)*65 + (t&7)*8 + j];
    ST8H(ycT + (size_t)d*LB + b*LL + l0, o);
  }
}

// K4a (MFMA): block = 64 pixels, 4 waves; LN via padded LDS stats (bf16 in);
// out_proj mfma (bf16 weights pre-staged); +xin -> xnew (bf16).
__global__ __launch_bounds__(256) void k4a_proj(
    const float* __restrict__ xmag, const float* __restrict__ xph,
    const float* __restrict__ onw_, const float* __restrict__ onb_,
    float* __restrict__ ws)
{
  const int i = blockIdx.y;
  const float* xin = i ? xph : xmag;
  const float* onw = onw_ + i*DI;
  const float* onb = onb_ + i*DI;
  float* base = ws + (size_t)i*ISTRIDE;
  const short* ycT = (const short*)(base + OFF_YCOMBT);
  const short* zT  = (const short*)(base + OFF_Z);
  const short* wb  = (const short*)(base + OFF_WB);
  const int t = threadIdx.x, lane = t & 63;
  const int wv = __builtin_amdgcn_readfirstlane(t >> 6);
  const int m = lane & 15, quad = lane >> 4;
  const int p0 = blockIdx.x*64;
  const int p = p0 + lane;

  __shared__ short ynlds[64*136];
  __shared__ short wlds[64*136];
  __shared__ float st[64][9];

  float yv[32];
  float s1=0.f, s2=0.f;
  #pragma unroll 8
  for(int c=0;c<32;++c){
    const float v = bf2f_(ycT[(size_t)(wv*32+c)*LB + p]);
    yv[c]=v; s1+=v; s2+=v*v;
  }
  st[lane][wv*2]=s1; st[lane][wv*2+1]=s2;
  __syncthreads();
  const float S1 = st[lane][0]+st[lane][2]+st[lane][4]+st[lane][6];
  const float S2 = st[lane][1]+st[lane][3]+st[lane][5]+st[lane][7];
  const float mu = S1*(1.f/DI);
  const float rs = rsqrtf(S2*(1.f/DI) - mu*mu + EPSF);
  #pragma unroll
  for(int cq=0;cq<8;++cq){
    short4 s4;
    #pragma unroll
    for(int e=0;e<4;++e){
      const int c = cq*4+e;
      const int d = wv*32 + c;
      ((short*)&s4)[e] = bf16_(((yv[c]-mu)*rs*onw[d] + onb[d]) * bf2f_(zT[(size_t)d*LB + p]));
    }
    *(short4*)&ynlds[lane*136 + wv*32 + cq*4] = s4;
  }
  {
    const int ol = t >> 2, seg = (t & 3)*32;
    const short* src = wb + WB_OPW + (size_t)ol*DI + seg;
    #pragma unroll
    for(int q=0;q<4;++q)
      *(v8s*)&wlds[ol*136 + seg + q*8] = ((const v8s*)src)[q];
  }
  __syncthreads();

  v4f accs[4];
  #pragma unroll
  for(int nt=0; nt<4; ++nt){
    v4f acc = (v4f){0.f,0.f,0.f,0.f};
    #pragma unroll
    for(int ks=0; ks<4; ++ks){
      const v8s a = *(const v8s*)&ynlds[(wv*16 + m)*136 + ks*32 + quad*8];
      const v8s b = *(const v8s*)&wlds[(nt*16 + m)*136 + ks*32 + quad*8];
      acc = __builtin_amdgcn_mfma_f32_16x16x32_bf16(a, b, acc, 0, 0, 0);
    }
    accs[nt] = acc;
  }
  short* xnew = (short*)(base + OFF_XNEW);
  #pragma unroll
  for(int nt=0; nt<4; ++nt){
    #pragma unroll
    for(int r=0;r<4;++r){
      const int pp = p0 + wv*16 + quad*4 + r;
      const int o = nt*16 + m;
      xnew[(size_t)pp*CC + o] = bf16_(accs[nt][r] + xin[(size_t)pp*CC + o]);
    }
  }
}

// K4b (MFMA, fused k5): 64-pixel tile, 4 waves; loops both instances in-block
// (same LDS footprint, barrier between); accumulates fc2+bias+residual in fp32
// regs and writes both output halves directly.
__global__ __launch_bounds__(256) void k4b_mlp(
    const float* __restrict__ n2w_, const float* __restrict__ n2b_,
    const float* __restrict__ f1b_, const float* __restrict__ f2b_,
    float* __restrict__ ws, float* __restrict__ out)
{
  const int t = threadIdx.x, lane = t & 63;
  const int wv = __builtin_amdgcn_readfirstlane(t >> 6);
  const int m = lane & 15, quad = lane >> 4;
  const int p0 = blockIdx.x*64;

  __shared__ short hlds[64*72];
  __shared__ short w1lds[128*72];
  __shared__ short glds[64*136];
  __shared__ short w2lds[64*136];

  float outsum[16];
  #pragma unroll
  for(int e=0;e<16;++e) outsum[e]=0.f;

  #pragma unroll 1
  for(int i=0;i<2;++i){
    float* base = ws + (size_t)i*ISTRIDE;
    const short* xnew = (const short*)(base + OFF_XNEW);
    const short* wb   = (const short*)(base + OFF_WB);
    const float* n2w = n2w_ + i*CC;
    const float* n2b = n2b_ + i*CC;
    const float* f1b = f1b_ + i*256;
    const float* f2b = f2b_ + i*CC;

    if(i) __syncthreads();   // protect LDS reuse across instances

    {
      float h2[64];
      const short* xr = xnew + (size_t)(p0 + lane)*CC;
      LD16H(h2, xr); LD16H((h2+16), xr+16); LD16H((h2+32), xr+32); LD16H((h2+48), xr+48);
      float s1=0.f, s2=0.f;
      #pragma unroll
      for(int c=0;c<CC;++c){ s1 += h2[c]; s2 += h2[c]*h2[c]; }
      const float mu = s1*(1.f/CC);
      const float rs = rsqrtf(s2*(1.f/CC) - mu*mu + EPSF);
      if(wv==0){
        #pragma unroll
        for(int q=0;q<8;++q){
          v8s s;
          #pragma unroll
          for(int e=0;e<8;++e){
            const int c = q*8+e;
            s[e] = bf16_((h2[c]-mu)*rs*n2w[c] + n2b[c]);
          }
          *(v8s*)&hlds[lane*72 + q*8] = s;
        }
      }
    }

    v4f acc2[4];
    #pragma unroll
    for(int n=0;n<4;++n) acc2[n] = (v4f){0.f,0.f,0.f,0.f};

    for(int h=0; h<2; ++h){
      if(h) __syncthreads();
      {
        const int jl = t >> 1, hc = (t & 1)*32;
        const short* src = wb + WB_F1W + (size_t)(h*128 + jl)*64 + hc;
        #pragma unroll
        for(int q=0;q<4;++q)
          *(v8s*)&w1lds[jl*72 + hc + q*8] = ((const v8s*)src)[q];
      }
      {
        const int ol = t >> 2, seg = (t & 3)*32;
        const short* src = wb + WB_F2W + (size_t)ol*256 + h*128 + seg;
        #pragma unroll
        for(int q=0;q<4;++q)
          *(v8s*)&w2lds[ol*136 + seg + q*8] = ((const v8s*)src)[q];
      }
      __syncthreads();
      #pragma unroll 2
      for(int nt=0; nt<8; ++nt){
        v4f acc = (v4f){0.f,0.f,0.f,0.f};
        #pragma unroll
        for(int ks=0; ks<2; ++ks){
          const v8s a = *(const v8s*)&hlds[(wv*16 + m)*72 + ks*32 + quad*8];
          const v8s b = *(const v8s*)&w1lds[(nt*16 + m)*72 + ks*32 + quad*8];
          acc = __builtin_amdgcn_mfma_f32_16x16x32_bf16(a, b, acc, 0, 0, 0);
        }
        const float bj = f1b[h*128 + nt*16 + m];
        #pragma unroll
        for(int r=0;r<4;++r){
          glds[(wv*16 + quad*4 + r)*136 + nt*16 + m] = bf16_(geluf_(acc[r] + bj));
        }
      }
      #pragma unroll
      for(int nt=0; nt<4; ++nt){
        v4f acc = acc2[nt];
        #pragma unroll
        for(int ks=0; ks<4; ++ks){
          const v8s a = *(const v8s*)&glds[(wv*16 + m)*136 + ks*32 + quad*8];
          const v8s b = *(const v8s*)&w2lds[(nt*16 + m)*136 + ks*32 + quad*8];
          acc = __builtin_amdgcn_mfma_f32_16x16x32_bf16(a, b, acc, 0, 0, 0);
        }
        acc2[nt] = acc;
      }
    }

    #pragma unroll
    for(int nt=0; nt<4; ++nt){
      const float bo = f2b[nt*16 + m];
      #pragma unroll
      for(int r=0;r<4;++r){
        const int pp = p0 + wv*16 + quad*4 + r;
        const int o  = nt*16 + m;
        outsum[nt*4+r] += acc2[nt][r] + bo + bf2f_(xnew[(size_t)pp*CC + o]);
      }
    }
  }

  #pragma unroll
  for(int nt=0; nt<4; ++nt){
    #pragma unroll
    for(int r=0;r<4;++r){
      const int pp = p0 + wv*16 + quad*4 + r;
      const int o  = nt*16 + m;
      out[(size_t)pp*CC + o] = outsum[nt*4+r];
      out[(size_t)NPIX + (size_t)pp*CC + o] = outsum[nt*4+r];
    }
  }
}

extern "C" void kernel_launch(void* const* d_in, const int* in_sizes, int n_in,
                              void* d_out, int out_size, void* d_ws, size_t ws_size,
                              hipStream_t stream)
{
  const float* mag  = (const float*)d_in[0];
  const float* ph   = (const float*)d_in[1];
  const float* n1w  = (const float*)d_in[2];
  const float* n1b  = (const float*)d_in[3];
  const float* ipw  = (const float*)d_in[4];
  const float* cw   = (const float*)d_in[5];
  const float* xpw  = (const float*)d_in[6];
  const float* dtw  = (const float*)d_in[7];
  const float* dtb  = (const float*)d_in[8];
  const float* alog = (const float*)d_in[9];
  const float* Ds   = (const float*)d_in[10];
  const float* onw  = (const float*)d_in[11];
  const float* onb  = (const float*)d_in[12];
  const float* opw  = (const float*)d_in[13];
  const float* n2w  = (const float*)d_in[14];
  const float* n2b  = (const float*)d_in[15];
  const float* f1w  = (const float*)d_in[16];
  const float* f1b  = (const float*)d_in[17];
  const float* f2w  = (const float*)d_in[18];
  const float* f2b  = (const float*)d_in[19];
  float* ws = (float*)d_ws;
  float* out = (float*)d_out;

  kw_prep     <<<dim3(56,2),   256, 0, stream>>>(ipw, opw, f1w, f2w, ws);
  k1_ln_inproj<<<dim3(512,2),  256, 0, stream>>>(mag, ph, n1w, n1b, ws);
  k2_dwconv   <<<dim3(1024,2), 256, 0, stream>>>(cw, ws);
  k3a_xproj   <<<dim3(16,16,2),256, 0, stream>>>(xpw, ws);
  k3b_scan    <<<dim3(1024,2), 512, 0, stream>>>(dtw, dtb, alog, Ds, ws);
  k4a_proj    <<<dim3(512,2),  256, 0, stream>>>(mag, ph, onw, onb, ws);
  k4b_mlp     <<<dim3(512),    256, 0, stream>>>(n2w, n2b, f1b, f2b, ws, out);
}

// Round 14
// 255.864 us; speedup vs baseline: 1.0086x; 1.0086x over previous
//
#include <hip/hip_runtime.h>
#include <math.h>

// Problem constants
#define LL   4096      // H*W
#define DI   128       // 2*C
#define CC   64        // C
#define BB   8         // batch
#define KK   4         // scan directions
#define LB   32768     // pixels per instance
#define NPIX 2097152   // B*H*W*C elements of s
#define EPSF 1e-5f
#define LOG2E 1.44269504089f
#define LN2F  0.69314718056f

// Workspace layout (float-indexed offsets; most regions hold bf16).
#define OFF_XCIN   ((size_t)0)
#define OFF_XCONV  ((size_t)4194304)
#define OFF_XCONVT ((size_t)8388608)
#define OFF_Z      ((size_t)12582912)
#define OFF_Y      ((size_t)16777216)
#define OFF_YT     ((size_t)20971520)
#define OFF_XDBL   ((size_t)25165824)   // bf16: 786432 shorts (lower half of region)
#define ISTRIDE    ((size_t)25952256)   // floats per instance
// Aliases (lifetime-disjoint reuse):
#define OFF_YCOMBT OFF_XCIN             // xcin dead after k2; ycombT (d-major) by k3b
#define OFF_XNEW   OFF_YT               // xnew (pixel-major bf16) by k4a
// bf16 weight block: dead upper part of the OFF_Y region.
#define OFF_WB     (OFF_Y + (size_t)2097152)
// short-offsets inside the weight block:
#define WB_IPW 0        // [256][64]
#define WB_OPW 16384    // [64][128]
#define WB_F1W 24576    // [256][64]
#define WB_F2W 40960    // [64][256]
#define WB_TOT 57344

typedef short v8s __attribute__((ext_vector_type(8)));
typedef float v4f __attribute__((ext_vector_type(4)));

__device__ __forceinline__ float fexp_(float x){ return __expf(x); }
__device__ __forceinline__ float silu_(float x){ return __fdividef(x, 1.f+__expf(-x)); }
__device__ __forceinline__ float geluf_(float x){ return 0.5f*x*(1.f+erff(x*0.70710678118f)); }
__device__ __forceinline__ short bf16_(float x){
  unsigned u = __float_as_uint(x);
  u += 0x7FFF + ((u>>16)&1);     // RNE
  return (short)(u>>16);
}
__device__ __forceinline__ float bf2f_(short s){
  return __uint_as_float(((unsigned)(unsigned short)s)<<16);
}

#define LD16(dst, ptr) { const float4* p4_=(const float4*)(ptr);                 \
  float4 v0_=p4_[0], v1_=p4_[1], v2_=p4_[2], v3_=p4_[3];                         \
  dst[0]=v0_.x; dst[1]=v0_.y; dst[2]=v0_.z; dst[3]=v0_.w;                        \
  dst[4]=v1_.x; dst[5]=v1_.y; dst[6]=v1_.z; dst[7]=v1_.w;                        \
  dst[8]=v2_.x; dst[9]=v2_.y; dst[10]=v2_.z; dst[11]=v2_.w;                      \
  dst[12]=v3_.x; dst[13]=v3_.y; dst[14]=v3_.z; dst[15]=v3_.w; }
// 16 bf16 (32B) -> 16 floats
#define LD16H(dst, ptr) { const v8s* p8_=(const v8s*)(ptr);                      \
  v8s a0_=p8_[0], a1_=p8_[1];                                                    \
  _Pragma("unroll") for(int e_=0;e_<8;++e_){ dst[e_]=bf2f_(a0_[e_]);             \
                                             dst[8+e_]=bf2f_(a1_[e_]); } }
// 16 bf16 reversed: dst[15-m] = ptr[m]
#define LD16HR(dst, ptr) { const v8s* p8_=(const v8s*)(ptr);                     \
  v8s a0_=p8_[0], a1_=p8_[1];                                                    \
  _Pragma("unroll") for(int e_=0;e_<8;++e_){ dst[15-e_]=bf2f_(a0_[e_]);          \
                                             dst[7-e_]=bf2f_(a1_[e_]); } }
// 16 floats -> 16 bf16 (2 v8s stores)
#define ST16H(ptr, srcv) { v8s o0_, o1_;                                         \
  _Pragma("unroll") for(int e_=0;e_<8;++e_){ o0_[e_]=bf16_(srcv[e_]);            \
                                             o1_[e_]=bf16_(srcv[8+e_]); }        \
  ((v8s*)(ptr))[0]=o0_; ((v8s*)(ptr))[1]=o1_; }

// KW: one-shot f32 -> bf16 conversion of all MFMA weight matrices into ws.
__global__ __launch_bounds__(256) void kw_prep(
    const float* __restrict__ ipw_, const float* __restrict__ opw_,
    const float* __restrict__ f1w_, const float* __restrict__ f2w_,
    float* __restrict__ ws)
{
  const int i = blockIdx.y;
  short* wb = (short*)(ws + (size_t)i*ISTRIDE + OFF_WB);
  const int e0 = blockIdx.x*1024 + threadIdx.x;
  #pragma unroll
  for(int k=0;k<4;++k){
    const int e = e0 + k*256;
    float v;
    if(e < WB_OPW)      v = ipw_[(size_t)i*16384 + e];
    else if(e < WB_F1W) v = opw_[(size_t)i*8192  + (e - WB_OPW)];
    else if(e < WB_F2W) v = f1w_[(size_t)i*16384 + (e - WB_F1W)];
    else                v = f2w_[(size_t)i*16384 + (e - WB_F2W)];
    wb[e] = bf16_(v);
  }
}

// K1 (MFMA): block = 64 pixels, 4 waves; LN -> bf16 hlds; ipw staged per half
// from pre-converted bf16 weights; outputs xcin (bf16, b,d,l) and zT (bf16,
// d-major silu).
__global__ __launch_bounds__(256) void k1_ln_inproj(
    const float* __restrict__ xmag, const float* __restrict__ xph,
    const float* __restrict__ n1w_, const float* __restrict__ n1b_,
    float* __restrict__ ws)
{
  const int i = blockIdx.y;
  const float* xin = i ? xph : xmag;
  const float* n1w = n1w_ + i*CC;
  const float* n1b = n1b_ + i*CC;
  float* base = ws + (size_t)i*ISTRIDE;
  const short* wb_ipw = (const short*)(base + OFF_WB) + WB_IPW;
  const int t = threadIdx.x, lane = t & 63;
  const int wv = __builtin_amdgcn_readfirstlane(t >> 6);
  const int m = lane & 15, quad = lane >> 4;
  const int p0 = blockIdx.x*64;
  const int b = p0 >> 12, l0 = p0 & (LL-1);

  __shared__ short hlds[64*72];
  __shared__ short w1lds[128*72];
  __shared__ float outs[128*68];

  {
    float hn[CC];
    const float* xr = xin + (size_t)(p0 + lane)*CC;
    LD16(hn, xr); LD16((hn+16), xr+16); LD16((hn+32), xr+32); LD16((hn+48), xr+48);
    float s1=0.f, s2=0.f;
    #pragma unroll
    for(int c=0;c<CC;++c){ s1 += hn[c]; s2 += hn[c]*hn[c]; }
    const float mu = s1*(1.f/CC);
    const float rs = rsqrtf(s2*(1.f/CC) - mu*mu + EPSF);
    if(wv==0){
      #pragma unroll
      for(int q=0;q<8;++q){
        v8s s;
        #pragma unroll
        for(int e=0;e<8;++e){
          const int c = q*8+e;
          s[e] = bf16_((hn[c]-mu)*rs*n1w[c] + n1b[c]);
        }
        *(v8s*)&hlds[lane*72 + q*8] = s;
      }
    }
  }

  for(int h=0; h<2; ++h){
    if(h) __syncthreads();
    {
      const int jl = t >> 1, hc = (t & 1)*32;
      const short* src = wb_ipw + (size_t)(h*128 + jl)*64 + hc;
      #pragma unroll
      for(int q=0;q<4;++q)
        *(v8s*)&w1lds[jl*72 + hc + q*8] = ((const v8s*)src)[q];
    }
    __syncthreads();
    #pragma unroll 2
    for(int nt=0; nt<8; ++nt){
      v4f acc = (v4f){0.f,0.f,0.f,0.f};
      #pragma unroll
      for(int ks=0; ks<2; ++ks){
        const v8s a = *(const v8s*)&hlds[(wv*16 + m)*72 + ks*32 + quad*8];
        const v8s bb = *(const v8s*)&w1lds[(nt*16 + m)*72 + ks*32 + quad*8];
        acc = __builtin_amdgcn_mfma_f32_16x16x32_bf16(a, bb, acc, 0, 0, 0);
      }
      *(float4*)&outs[(nt*16 + m)*68 + wv*16 + quad*4] =
          make_float4(acc[0], acc[1], acc[2], acc[3]);
    }
    __syncthreads();
    const int jl = t >> 1, hc = (t & 1)*32;
    if(h==0){
      short* xcb = (short*)(base + OFF_XCIN) + (size_t)b*DI*LL + (size_t)jl*LL + l0 + hc;
      const float* so = &outs[jl*68 + hc];
      ST16H(xcb, so);
      ST16H(xcb+16, (so+16));
    } else {
      short* zr = (short*)(base + OFF_Z) + (size_t)jl*LB + p0 + hc;
      float tmp[32];
      #pragma unroll
      for(int e=0;e<32;++e) tmp[e] = silu_(outs[jl*68 + hc + e]);
      ST16H(zr, tmp);
      ST16H(zr+16, (tmp+16));
    }
  }
}

// K2: depthwise 3x3 conv + silu; bf16 in (xcin), bf16 out (xconv/xconvT).
// v8s-vectorized input load into a zero-padded 66x66 fp32 tile -> branch-free
// 3x3 window (no bounds checks).
__global__ __launch_bounds__(256) void k2_dwconv(
    const float* __restrict__ cw_, float* __restrict__ ws)
{
  const int i = blockIdx.y;
  const int bd = blockIdx.x;
  const int d = bd & (DI-1);
  const float* cw = cw_ + i*DI*9 + d*9;
  const short* xcin = (const short*)(ws + (size_t)i*ISTRIDE + OFF_XCIN) + (size_t)bd*LL;
  short* xconv  = (short*)(ws + (size_t)i*ISTRIDE + OFF_XCONV ) + (size_t)bd*LL;
  short* xconvT = (short*)(ws + (size_t)i*ISTRIDE + OFF_XCONVT) + (size_t)bd*LL;
  __shared__ float tin[66*66];     // zero-padded border
  __shared__ float tout[64*65];
  const int t = threadIdx.x;
  float w9[9];
  #pragma unroll
  for(int q=0;q<9;++q) w9[q] = cw[q];
  // zero-fill (border matters; interior overwritten below after barrier)
  for(int idx=t; idx<66*66; idx+=256) tin[idx] = 0.f;
  __syncthreads();
  // vectorized interior fill: 2 x v8s per thread
  #pragma unroll
  for(int pass=0; pass<2; ++pass){
    const int e = t*8 + pass*2048;           // element index, 8-aligned
    const int row = e >> 6, col = e & 63;
    const v8s v = *(const v8s*)&xcin[e];
    #pragma unroll
    for(int q=0;q<8;++q)
      tin[(row+1)*66 + col+1 + q] = bf2f_(v[q]);
  }
  __syncthreads();
  const int w = t & 63, hb = (t>>6)*16;
  #pragma unroll
  for(int r=0;r<16;++r){
    const int h = hb + r;
    const float* tc = &tin[h*66 + w];        // (h-1+1)*66 + (w-1+1): window origin
    float acc = tc[0]*w9[0] + tc[1]*w9[1] + tc[2]*w9[2]
              + tc[66]*w9[3] + tc[67]*w9[4] + tc[68]*w9[5]
              + tc[132]*w9[6] + tc[133]*w9[7] + tc[134]*w9[8];
    const float o = silu_(acc);
    tout[h*65+w] = o;
    xconv[h*64+w] = bf16_(o);
  }
  __syncthreads();
  const int hcol = t & 63, wb = (t>>6)*16;
  #pragma unroll
  for(int r=0;r<16;++r){
    const int wp = wb + r;
    xconvT[wp*64 + hcol] = bf16_(tout[hcol*65 + wp]);
  }
}

// K3a: paired-direction x_proj from bf16 src; xdbl stored bf16.
__global__ __launch_bounds__(256) void k3a_xproj(
    const float* __restrict__ xpw_, float* __restrict__ ws)
{
  const int i = blockIdx.z;
  const int b = blockIdx.y >> 1;
  const int kp = blockIdx.y & 1;
  const int l = blockIdx.x*256 + threadIdx.x;   // source index
  const short* src = (const short*)(ws + (size_t)i*ISTRIDE + (kp? OFF_XCONVT : OFF_XCONV))
                     + (size_t)b*DI*LL;
  const float* xpwF = xpw_ + i*KK*6*DI + kp*6*DI;
  const float* xpwB = xpw_ + i*KK*6*DI + (kp+2)*6*DI;
  float accF[6] = {0,0,0,0,0,0};
  float accB[6] = {0,0,0,0,0,0};
  for(int d=0; d<DI; ++d){
    const float xv = bf2f_(src[(size_t)d*LL + l]);
    #pragma unroll
    for(int c=0;c<6;++c){
      accF[c] += xv * xpwF[c*DI + d];
      accB[c] += xv * xpwB[c*DI + d];
    }
  }
  short* xdF = (short*)(ws + (size_t)i*ISTRIDE + OFF_XDBL) + (size_t)(b*KK+kp  )*6*LL;
  short* xdB = (short*)(ws + (size_t)i*ISTRIDE + OFF_XDBL) + (size_t)(b*KK+kp+2)*6*LL;
  #pragma unroll
  for(int c=0;c<6;++c) xdF[(size_t)c*LL + l] = bf16_(accF[c]);
  #pragma unroll
  for(int c=0;c<6;++c) xdB[(size_t)c*LL + (LL-1-l)] = bf16_(accB[c]);
}

// K3b (merged): one block per (b,d); computes BOTH direction pairs (kp=0,1),
// combines y + transpose(yT) in an LDS fp32 tile, writes d-major bf16 ycombT.
// exp2-domain softplus; scan in t-units, ln2 folded at the C-multiply.
// launch_bounds (256,3): MEASURED-BEST config, bracketed across 6 variants:
// THIS FORM 49-51us; 512x8 56.3 (ILP loss > TLP gain); plain softplus 58.6;
// F/B phase-split 62.6; fp32-xdbl 73.6; (256,6) spills 110. ILP (16 loads in
// flight, interleaved F/B) is what hides latency here. Do not restructure.
__global__ __launch_bounds__(256,3) void k3b_scan(
    const float* __restrict__ dtw_, const float* __restrict__ dtb_,
    const float* __restrict__ alog_, const float* __restrict__ Ds_,
    float* __restrict__ ws)
{
  const int gid = blockIdx.x;           // b*128 + d
  const int i = blockIdx.y;
  const int d  = gid & (DI-1);
  const int b  = gid >> 7;
  const int t = threadIdx.x, lane = t & 63, wv = t >> 6;
  float* base = ws + (size_t)i*ISTRIDE;
  const int l0 = t*16;
  const int s0 = LL - 16 - l0;

  __shared__ float tile[64*65];
  __shared__ float wAg[4], wBg[4], vAg[4], vBg[4];

  #pragma unroll 1
  for(int kp=0; kp<2; ++kp){
    const short* src = (const short*)(base + (kp? OFF_XCONVT : OFF_XCONV)) + (size_t)(b*DI+d)*LL;
    const short* xdF = (const short*)(base + OFF_XDBL) + (size_t)(b*KK+kp  )*6*LL;
    const short* xdB = (const short*)(base + OFF_XDBL) + (size_t)(b*KK+kp+2)*6*LL;
    const int kdF = kp*DI + d, kdB = (kp+2)*DI + d;
    const float4 wF = ((const float4*)dtw_)[i*KK*DI + kdF];
    const float4 wB = ((const float4*)dtw_)[i*KK*DI + kdB];
    const float biasF = dtb_[i*KK*DI + kdF], biasB = dtb_[i*KK*DI + kdB];
    const float AvF = -fexp_(alog_[i*KK*DI + kdF]);
    const float AvB = -fexp_(alog_[i*KK*DI + kdB]);
    const float Dsum = Ds_[i*KK*DI + kdF] + Ds_[i*KK*DI + kdB];

    float vX[16], aF[16], bF[16], aB[16], bB[16];
    float fA = 1.f, fB = 0.f, gA = 1.f, gB = 0.f;
    LD16H(vX, src + l0);

    {
      float pre[16], r0[16];
      LD16H(r0, xdF + 0*LL + l0);
      #pragma unroll
      for(int j=0;j<16;++j) pre[j] = biasF + wF.x*r0[j];
      LD16H(r0, xdF + 1*LL + l0);
      #pragma unroll
      for(int j=0;j<16;++j) pre[j] += wF.y*r0[j];
      LD16H(r0, xdF + 2*LL + l0);
      #pragma unroll
      for(int j=0;j<16;++j) pre[j] += wF.z*r0[j];
      LD16H(r0, xdF + 3*LL + l0);
      #pragma unroll
      for(int j=0;j<16;++j) pre[j] += wF.w*r0[j];
      LD16H(r0, xdF + 4*LL + l0);   // Bs
      #pragma unroll
      for(int j=0;j<16;++j){
        const float tt = __builtin_log2f(1.f + __builtin_exp2f(pre[j]*LOG2E));
        aF[j] = __builtin_exp2f(AvF*tt);
        bF[j] = tt*r0[j]*vX[j];
        fB = fB*aF[j] + bF[j];
        fA *= aF[j];
      }
    }
    {
      float pre[16], r0[16];
      LD16HR(r0, xdB + 0*LL + s0);
      #pragma unroll
      for(int j=0;j<16;++j) pre[j] = biasB + wB.x*r0[j];
      LD16HR(r0, xdB + 1*LL + s0);
      #pragma unroll
      for(int j=0;j<16;++j) pre[j] += wB.y*r0[j];
      LD16HR(r0, xdB + 2*LL + s0);
      #pragma unroll
      for(int j=0;j<16;++j) pre[j] += wB.z*r0[j];
      LD16HR(r0, xdB + 3*LL + s0);
      #pragma unroll
      for(int j=0;j<16;++j) pre[j] += wB.w*r0[j];
      LD16HR(r0, xdB + 4*LL + s0);  // Bs reversed
      #pragma unroll
      for(int j=15;j>=0;--j){
        const float tt = __builtin_log2f(1.f + __builtin_exp2f(pre[j]*LOG2E));
        aB[j] = __builtin_exp2f(AvB*tt);
        bB[j] = tt*r0[j]*vX[j];
        gB = gB*aB[j] + bB[j];
        gA *= aB[j];
      }
    }

    #pragma unroll
    for(int off=1; off<64; off<<=1){
      const float aL = __shfl_up(fA, off);
      const float bL = __shfl_up(fB, off);
      if(lane >= off){ fB = bL*fA + fB; fA = aL*fA; }
    }
    float pA = __shfl_up(fA, 1), pB = __shfl_up(fB, 1);
    if(lane==0){ pA=1.f; pB=0.f; }
    #pragma unroll
    for(int off=1; off<64; off<<=1){
      const float aR = __shfl_down(gA, off);
      const float bR = __shfl_down(gB, off);
      if(lane + off < 64){ gB = gA*bR + gB; gA = gA*aR; }
    }
    float qA = __shfl_down(gA, 1), qB = __shfl_down(gB, 1);
    if(lane==63){ qA=1.f; qB=0.f; }

    if(kp) __syncthreads();
    if(lane==63){ wAg[wv]=fA; wBg[wv]=fB; }
    if(lane==0){ vAg[wv]=gA; vBg[wv]=gB; }
    __syncthreads();
    float eB=0.f;
    for(int u=0; u<wv; ++u){ eB = wAg[u]*eB + wBg[u]; }
    float rB=0.f;
    for(int u=3; u>wv; --u){ rB = vAg[u]*rB + vBg[u]; }

    float hf = pA*eB + pB;
    float hb = qA*rB + qB;

    float out[16], cc[16];
    LD16H(cc, xdF + 5*LL + l0);
    #pragma unroll
    for(int j=0;j<16;++j){
      hf = aF[j]*hf + bF[j];
      out[j] = hf*(cc[j]*LN2F) + Dsum*vX[j];   // ln2 fold (scan in t-units)
    }
    LD16HR(cc, xdB + 5*LL + s0);
    #pragma unroll
    for(int j=15;j>=0;--j){
      hb = aB[j]*hb + bB[j];
      out[j] += hb*(cc[j]*LN2F);
    }

    if(kp==0){
      #pragma unroll
      for(int j=0;j<16;++j){
        const int l = l0 + j;
        tile[(l>>6)*65 + (l&63)] = out[j];
      }
    } else {
      #pragma unroll
      for(int j=0;j<16;++j){
        const int q = l0 + j;
        tile[(q&63)*65 + (q>>6)] += out[j];
      }
    }
  }

  __syncthreads();
  {
    short* ycT = (short*)(base + OFF_YCOMBT);
    float o[16];
    #pragma unroll
    for(int j=0;j<16;++j)
      o[j] = tile[(t>>2)*65 + (t&3)*16 + j];
    ST16H(ycT + (size_t)d*LB + b*LL + l0, o);
  }
}

// K4a (MFMA): block = 64 pixels, 4 waves; LN via padded LDS stats (bf16 in);
// out_proj mfma (bf16 weights pre-staged); +xin -> xnew (bf16).
__global__ __launch_bounds__(256) void k4a_proj(
    const float* __restrict__ xmag, const float* __restrict__ xph,
    const float* __restrict__ onw_, const float* __restrict__ onb_,
    float* __restrict__ ws)
{
  const int i = blockIdx.y;
  const float* xin = i ? xph : xmag;
  const float* onw = onw_ + i*DI;
  const float* onb = onb_ + i*DI;
  float* base = ws + (size_t)i*ISTRIDE;
  const short* ycT = (const short*)(base + OFF_YCOMBT);
  const short* zT  = (const short*)(base + OFF_Z);
  const short* wb  = (const short*)(base + OFF_WB);
  const int t = threadIdx.x, lane = t & 63;
  const int wv = __builtin_amdgcn_readfirstlane(t >> 6);
  const int m = lane & 15, quad = lane >> 4;
  const int p0 = blockIdx.x*64;
  const int p = p0 + lane;

  __shared__ short ynlds[64*136];
  __shared__ short wlds[64*136];
  __shared__ float st[64][9];

  float yv[32];
  float s1=0.f, s2=0.f;
  #pragma unroll 8
  for(int c=0;c<32;++c){
    const float v = bf2f_(ycT[(size_t)(wv*32+c)*LB + p]);
    yv[c]=v; s1+=v; s2+=v*v;
  }
  st[lane][wv*2]=s1; st[lane][wv*2+1]=s2;
  __syncthreads();
  const float S1 = st[lane][0]+st[lane][2]+st[lane][4]+st[lane][6];
  const float S2 = st[lane][1]+st[lane][3]+st[lane][5]+st[lane][7];
  const float mu = S1*(1.f/DI);
  const float rs = rsqrtf(S2*(1.f/DI) - mu*mu + EPSF);
  #pragma unroll
  for(int cq=0;cq<8;++cq){
    short4 s4;
    #pragma unroll
    for(int e=0;e<4;++e){
      const int c = cq*4+e;
      const int d = wv*32 + c;
      ((short*)&s4)[e] = bf16_(((yv[c]-mu)*rs*onw[d] + onb[d]) * bf2f_(zT[(size_t)d*LB + p]));
    }
    *(short4*)&ynlds[lane*136 + wv*32 + cq*4] = s4;
  }
  {
    const int ol = t >> 2, seg = (t & 3)*32;
    const short* src = wb + WB_OPW + (size_t)ol*DI + seg;
    #pragma unroll
    for(int q=0;q<4;++q)
      *(v8s*)&wlds[ol*136 + seg + q*8] = ((const v8s*)src)[q];
  }
  __syncthreads();

  v4f accs[4];
  #pragma unroll
  for(int nt=0; nt<4; ++nt){
    v4f acc = (v4f){0.f,0.f,0.f,0.f};
    #pragma unroll
    for(int ks=0; ks<4; ++ks){
      const v8s a = *(const v8s*)&ynlds[(wv*16 + m)*136 + ks*32 + quad*8];
      const v8s b = *(const v8s*)&wlds[(nt*16 + m)*136 + ks*32 + quad*8];
      acc = __builtin_amdgcn_mfma_f32_16x16x32_bf16(a, b, acc, 0, 0, 0);
    }
    accs[nt] = acc;
  }
  short* xnew = (short*)(base + OFF_XNEW);
  #pragma unroll
  for(int nt=0; nt<4; ++nt){
    #pragma unroll
    for(int r=0;r<4;++r){
      const int pp = p0 + wv*16 + quad*4 + r;
      const int o = nt*16 + m;
      xnew[(size_t)pp*CC + o] = bf16_(accs[nt][r] + xin[(size_t)pp*CC + o]);
    }
  }
}

// K4b (MFMA, fused k5): 64-pixel tile, 4 waves; loops both instances in-block
// (same LDS footprint, barrier between); accumulates fc2+bias+residual in fp32
// regs and writes both output halves directly.
__global__ __launch_bounds__(256) void k4b_mlp(
    const float* __restrict__ n2w_, const float* __restrict__ n2b_,
    const float* __restrict__ f1b_, const float* __restrict__ f2b_,
    float* __restrict__ ws, float* __restrict__ out)
{
  const int t = threadIdx.x, lane = t & 63;
  const int wv = __builtin_amdgcn_readfirstlane(t >> 6);
  const int m = lane & 15, quad = lane >> 4;
  const int p0 = blockIdx.x*64;

  __shared__ short hlds[64*72];
  __shared__ short w1lds[128*72];
  __shared__ short glds[64*136];
  __shared__ short w2lds[64*136];

  float outsum[16];
  #pragma unroll
  for(int e=0;e<16;++e) outsum[e]=0.f;

  #pragma unroll 1
  for(int i=0;i<2;++i){
    float* base = ws + (size_t)i*ISTRIDE;
    const short* xnew = (const short*)(base + OFF_XNEW);
    const short* wb   = (const short*)(base + OFF_WB);
    const float* n2w = n2w_ + i*CC;
    const float* n2b = n2b_ + i*CC;
    const float* f1b = f1b_ + i*256;
    const float* f2b = f2b_ + i*CC;

    if(i) __syncthreads();   // protect LDS reuse across instances

    {
      float h2[64];
      const short* xr = xnew + (size_t)(p0 + lane)*CC;
      LD16H(h2, xr); LD16H((h2+16), xr+16); LD16H((h2+32), xr+32); LD16H((h2+48), xr+48);
      float s1=0.f, s2=0.f;
      #pragma unroll
      for(int c=0;c<CC;++c){ s1 += h2[c]; s2 += h2[c]*h2[c]; }
      const float mu = s1*(1.f/CC);
      const float rs = rsqrtf(s2*(1.f/CC) - mu*mu + EPSF);
      if(wv==0){
        #pragma unroll
        for(int q=0;q<8;++q){
          v8s s;
          #pragma unroll
          for(int e=0;e<8;++e){
            const int c = q*8+e;
            s[e] = bf16_((h2[c]-mu)*rs*n2w[c] + n2b[c]);
          }
          *(v8s*)&hlds[lane*72 + q*8] = s;
        }
      }
    }

    v4f acc2[4];
    #pragma unroll
    for(int n=0;n<4;++n) acc2[n] = (v4f){0.f,0.f,0.f,0.f};

    for(int h=0; h<2; ++h){
      if(h) __syncthreads();
      {
        const int jl = t >> 1, hc = (t & 1)*32;
        const short* src = wb + WB_F1W + (size_t)(h*128 + jl)*64 + hc;
        #pragma unroll
        for(int q=0;q<4;++q)
          *(v8s*)&w1lds[jl*72 + hc + q*8] = ((const v8s*)src)[q];
      }
      {
        const int ol = t >> 2, seg = (t & 3)*32;
        const short* src = wb + WB_F2W + (size_t)ol*256 + h*128 + seg;
        #pragma unroll
        for(int q=0;q<4;++q)
          *(v8s*)&w2lds[ol*136 + seg + q*8] = ((const v8s*)src)[q];
      }
      __syncthreads();
      #pragma unroll 2
      for(int nt=0; nt<8; ++nt){
        v4f acc = (v4f){0.f,0.f,0.f,0.f};
        #pragma unroll
        for(int ks=0; ks<2; ++ks){
          const v8s a = *(const v8s*)&hlds[(wv*16 + m)*72 + ks*32 + quad*8];
          const v8s b = *(const v8s*)&w1lds[(nt*16 + m)*72 + ks*32 + quad*8];
          acc = __builtin_amdgcn_mfma_f32_16x16x32_bf16(a, b, acc, 0, 0, 0);
        }
        const float bj = f1b[h*128 + nt*16 + m];
        #pragma unroll
        for(int r=0;r<4;++r){
          glds[(wv*16 + quad*4 + r)*136 + nt*16 + m] = bf16_(geluf_(acc[r] + bj));
        }
      }
      #pragma unroll
      for(int nt=0; nt<4; ++nt){
        v4f acc = acc2[nt];
        #pragma unroll
        for(int ks=0; ks<4; ++ks){
          const v8s a = *(const v8s*)&glds[(wv*16 + m)*136 + ks*32 + quad*8];
          const v8s b = *(const v8s*)&w2lds[(nt*16 + m)*136 + ks*32 + quad*8];
          acc = __builtin_amdgcn_mfma_f32_16x16x32_bf16(a, b, acc, 0, 0, 0);
        }
        acc2[nt] = acc;
      }
    }

    #pragma unroll
    for(int nt=0; nt<4; ++nt){
      const float bo = f2b[nt*16 + m];
      #pragma unroll
      for(int r=0;r<4;++r){
        const int pp = p0 + wv*16 + quad*4 + r;
        const int o  = nt*16 + m;
        outsum[nt*4+r] += acc2[nt][r] + bo + bf2f_(xnew[(size_t)pp*CC + o]);
      }
    }
  }

  #pragma unroll
  for(int nt=0; nt<4; ++nt){
    #pragma unroll
    for(int r=0;r<4;++r){
      const int pp = p0 + wv*16 + quad*4 + r;
      const int o  = nt*16 + m;
      out[(size_t)pp*CC + o] = outsum[nt*4+r];
      out[(size_t)NPIX + (size_t)pp*CC + o] = outsum[nt*4+r];
    }
  }
}

extern "C" void kernel_launch(void* const* d_in, const int* in_sizes, int n_in,
                              void* d_out, int out_size, void* d_ws, size_t ws_size,
                              hipStream_t stream)
{
  const float* mag  = (const float*)d_in[0];
  const float* ph   = (const float*)d_in[1];
  const float* n1w  = (const float*)d_in[2];
  const float* n1b  = (const float*)d_in[3];
  const float* ipw  = (const float*)d_in[4];
  const float* cw   = (const float*)d_in[5];
  const float* xpw  = (const float*)d_in[6];
  const float* dtw  = (const float*)d_in[7];
  const float* dtb  = (const float*)d_in[8];
  const float* alog = (const float*)d_in[9];
  const float* Ds   = (const float*)d_in[10];
  const float* onw  = (const float*)d_in[11];
  const float* onb  = (const float*)d_in[12];
  const float* opw  = (const float*)d_in[13];
  const float* n2w  = (const float*)d_in[14];
  const float* n2b  = (const float*)d_in[15];
  const float* f1w  = (const float*)d_in[16];
  const float* f1b  = (const float*)d_in[17];
  const float* f2w  = (const float*)d_in[18];
  const float* f2b  = (const float*)d_in[19];
  float* ws = (float*)d_ws;
  float* out = (float*)d_out;

  kw_prep     <<<dim3(56,2),   256, 0, stream>>>(ipw, opw, f1w, f2w, ws);
  k1_ln_inproj<<<dim3(512,2),  256, 0, stream>>>(mag, ph, n1w, n1b, ws);
  k2_dwconv   <<<dim3(1024,2), 256, 0, stream>>>(cw, ws);
  k3a_xproj   <<<dim3(16,16,2),256, 0, stream>>>(xpw, ws);
  k3b_scan    <<<dim3(1024,2), 256, 0, stream>>>(dtw, dtb, alog, Ds, ws);
  k4a_proj    <<<dim3(512,2),  256, 0, stream>>>(mag, ph, onw, onb, ws);
  k4b_mlp     <<<dim3(512),    256, 0, stream>>>(n2w, n2b, f1b, f2b, ws, out);
}

// Round 17
// 246.099 us; speedup vs baseline: 1.0486x; 1.0397x over previous
//
#include <hip/hip_runtime.h>
#include <math.h>

// Problem constants
#define LL   4096      // H*W
#define DI   128       // 2*C
#define CC   64        // C
#define BB   8         // batch
#define KK   4         // scan directions
#define LB   32768     // pixels per instance
#define NPIX 2097152   // B*H*W*C elements of s
#define EPSF 1e-5f
#define LOG2E 1.44269504089f
#define LN2F  0.69314718056f

// Workspace layout (float-indexed offsets; most regions hold bf16).
#define OFF_XCIN   ((size_t)0)
#define OFF_XCONV  ((size_t)4194304)
#define OFF_XCONVT ((size_t)8388608)
#define OFF_Z      ((size_t)12582912)
#define OFF_Y      ((size_t)16777216)
#define OFF_YT     ((size_t)20971520)
#define OFF_XDBL   ((size_t)25165824)   // bf16: 786432 shorts (lower half of region)
#define ISTRIDE    ((size_t)25952256)   // floats per instance
// Aliases (lifetime-disjoint reuse):
#define OFF_YCOMBT OFF_XCIN             // xcin dead after k2; ycombT (d-major) by k3b
#define OFF_XNEW   OFF_YT               // xnew (pixel-major bf16) by k4a
// bf16 weight block: dead upper part of the OFF_Y region.
#define OFF_WB     (OFF_Y + (size_t)2097152)
// short-offsets inside the weight block:
#define WB_IPW 0        // [256][64]
#define WB_OPW 16384    // [64][128]
#define WB_F1W 24576    // [256][64]
#define WB_F2W 40960    // [64][256]
#define WB_TOT 57344

typedef short v8s __attribute__((ext_vector_type(8)));
typedef float v4f __attribute__((ext_vector_type(4)));

__device__ __forceinline__ float fexp_(float x){ return __expf(x); }
__device__ __forceinline__ float silu_(float x){ return __fdividef(x, 1.f+__expf(-x)); }
__device__ __forceinline__ float geluf_(float x){ return 0.5f*x*(1.f+erff(x*0.70710678118f)); }
__device__ __forceinline__ short bf16_(float x){
  unsigned u = __float_as_uint(x);
  u += 0x7FFF + ((u>>16)&1);     // RNE
  return (short)(u>>16);
}
__device__ __forceinline__ float bf2f_(short s){
  return __uint_as_float(((unsigned)(unsigned short)s)<<16);
}

#define LD16(dst, ptr) { const float4* p4_=(const float4*)(ptr);                 \
  float4 v0_=p4_[0], v1_=p4_[1], v2_=p4_[2], v3_=p4_[3];                         \
  dst[0]=v0_.x; dst[1]=v0_.y; dst[2]=v0_.z; dst[3]=v0_.w;                        \
  dst[4]=v1_.x; dst[5]=v1_.y; dst[6]=v1_.z; dst[7]=v1_.w;                        \
  dst[8]=v2_.x; dst[9]=v2_.y; dst[10]=v2_.z; dst[11]=v2_.w;                      \
  dst[12]=v3_.x; dst[13]=v3_.y; dst[14]=v3_.z; dst[15]=v3_.w; }
// 16 bf16 (32B) -> 16 floats
#define LD16H(dst, ptr) { const v8s* p8_=(const v8s*)(ptr);                      \
  v8s a0_=p8_[0], a1_=p8_[1];                                                    \
  _Pragma("unroll") for(int e_=0;e_<8;++e_){ dst[e_]=bf2f_(a0_[e_]);             \
                                             dst[8+e_]=bf2f_(a1_[e_]); } }
// 16 bf16 reversed: dst[15-m] = ptr[m]
#define LD16HR(dst, ptr) { const v8s* p8_=(const v8s*)(ptr);                     \
  v8s a0_=p8_[0], a1_=p8_[1];                                                    \
  _Pragma("unroll") for(int e_=0;e_<8;++e_){ dst[15-e_]=bf2f_(a0_[e_]);          \
                                             dst[7-e_]=bf2f_(a1_[e_]); } }
// 16 floats -> 16 bf16 (2 v8s stores)
#define ST16H(ptr, srcv) { v8s o0_, o1_;                                         \
  _Pragma("unroll") for(int e_=0;e_<8;++e_){ o0_[e_]=bf16_(srcv[e_]);            \
                                             o1_[e_]=bf16_(srcv[8+e_]); }        \
  ((v8s*)(ptr))[0]=o0_; ((v8s*)(ptr))[1]=o1_; }

// KW: one-shot f32 -> bf16 conversion of all MFMA weight matrices into ws.
__global__ __launch_bounds__(256) void kw_prep(
    const float* __restrict__ ipw_, const float* __restrict__ opw_,
    const float* __restrict__ f1w_, const float* __restrict__ f2w_,
    float* __restrict__ ws)
{
  const int i = blockIdx.y;
  short* wb = (short*)(ws + (size_t)i*ISTRIDE + OFF_WB);
  const int e0 = blockIdx.x*1024 + threadIdx.x;
  #pragma unroll
  for(int k=0;k<4;++k){
    const int e = e0 + k*256;
    float v;
    if(e < WB_OPW)      v = ipw_[(size_t)i*16384 + e];
    else if(e < WB_F1W) v = opw_[(size_t)i*8192  + (e - WB_OPW)];
    else if(e < WB_F2W) v = f1w_[(size_t)i*16384 + (e - WB_F1W)];
    else                v = f2w_[(size_t)i*16384 + (e - WB_F2W)];
    wb[e] = bf16_(v);
  }
}

// K1 (MFMA): block = 64 pixels, 4 waves; LN distributed across ALL threads
// (thread t owns pixel t>>2, channels (t&3)*16..+16; quad shfl_xor reduce) --
// removes the old 4x-redundant per-wave load+stats. ipw staged per half from
// pre-converted bf16 weights; outputs xcin (bf16, b,d,l) and zT (bf16 silu).
__global__ __launch_bounds__(256) void k1_ln_inproj(
    const float* __restrict__ xmag, const float* __restrict__ xph,
    const float* __restrict__ n1w_, const float* __restrict__ n1b_,
    float* __restrict__ ws)
{
  const int i = blockIdx.y;
  const float* xin = i ? xph : xmag;
  const float* n1w = n1w_ + i*CC;
  const float* n1b = n1b_ + i*CC;
  float* base = ws + (size_t)i*ISTRIDE;
  const short* wb_ipw = (const short*)(base + OFF_WB) + WB_IPW;
  const int t = threadIdx.x, lane = t & 63;
  const int wv = __builtin_amdgcn_readfirstlane(t >> 6);
  const int m = lane & 15, quad = lane >> 4;
  const int p0 = blockIdx.x*64;
  const int b = p0 >> 12, l0 = p0 & (LL-1);

  __shared__ short hlds[64*72];
  __shared__ short w1lds[128*72];
  __shared__ float outs[128*68];

  {
    const int pix = t >> 2, seg = (t & 3)*16;
    float hn[16];
    LD16(hn, xin + (size_t)(p0 + pix)*CC + seg);
    float s1=0.f, s2=0.f;
    #pragma unroll
    for(int c=0;c<16;++c){ s1 += hn[c]; s2 += hn[c]*hn[c]; }
    s1 += __shfl_xor(s1, 1); s2 += __shfl_xor(s2, 1);
    s1 += __shfl_xor(s1, 2); s2 += __shfl_xor(s2, 2);
    const float mu = s1*(1.f/CC);
    const float rs = rsqrtf(s2*(1.f/CC) - mu*mu + EPSF);
    v8s o0, o1;
    #pragma unroll
    for(int e=0;e<8;++e){
      o0[e] = bf16_((hn[e]  -mu)*rs*n1w[seg+e]   + n1b[seg+e]);
      o1[e] = bf16_((hn[8+e]-mu)*rs*n1w[seg+8+e] + n1b[seg+8+e]);
    }
    *(v8s*)&hlds[pix*72 + seg]     = o0;
    *(v8s*)&hlds[pix*72 + seg + 8] = o1;
  }

  for(int h=0; h<2; ++h){
    if(h) __syncthreads();
    {
      const int jl = t >> 1, hc = (t & 1)*32;
      const short* src = wb_ipw + (size_t)(h*128 + jl)*64 + hc;
      #pragma unroll
      for(int q=0;q<4;++q)
        *(v8s*)&w1lds[jl*72 + hc + q*8] = ((const v8s*)src)[q];
    }
    __syncthreads();
    #pragma unroll 2
    for(int nt=0; nt<8; ++nt){
      v4f acc = (v4f){0.f,0.f,0.f,0.f};
      #pragma unroll
      for(int ks=0; ks<2; ++ks){
        const v8s a = *(const v8s*)&hlds[(wv*16 + m)*72 + ks*32 + quad*8];
        const v8s bb = *(const v8s*)&w1lds[(nt*16 + m)*72 + ks*32 + quad*8];
        acc = __builtin_amdgcn_mfma_f32_16x16x32_bf16(a, bb, acc, 0, 0, 0);
      }
      *(float4*)&outs[(nt*16 + m)*68 + wv*16 + quad*4] =
          make_float4(acc[0], acc[1], acc[2], acc[3]);
    }
    __syncthreads();
    const int jl = t >> 1, hc = (t & 1)*32;
    if(h==0){
      short* xcb = (short*)(base + OFF_XCIN) + (size_t)b*DI*LL + (size_t)jl*LL + l0 + hc;
      const float* so = &outs[jl*68 + hc];
      ST16H(xcb, so);
      ST16H(xcb+16, (so+16));
    } else {
      short* zr = (short*)(base + OFF_Z) + (size_t)jl*LB + p0 + hc;
      float tmp[32];
      #pragma unroll
      for(int e=0;e<32;++e) tmp[e] = silu_(outs[jl*68 + hc + e]);
      ST16H(zr, tmp);
      ST16H(zr+16, (tmp+16));
    }
  }
}

// K2: depthwise 3x3 conv + silu; bf16 in (xcin), bf16 out (xconv/xconvT).
// v8s-vectorized input load into a zero-padded 66x66 fp32 tile -> branch-free
// 3x3 window (no bounds checks).
__global__ __launch_bounds__(256) void k2_dwconv(
    const float* __restrict__ cw_, float* __restrict__ ws)
{
  const int i = blockIdx.y;
  const int bd = blockIdx.x;
  const int d = bd & (DI-1);
  const float* cw = cw_ + i*DI*9 + d*9;
  const short* xcin = (const short*)(ws + (size_t)i*ISTRIDE + OFF_XCIN) + (size_t)bd*LL;
  short* xconv  = (short*)(ws + (size_t)i*ISTRIDE + OFF_XCONV ) + (size_t)bd*LL;
  short* xconvT = (short*)(ws + (size_t)i*ISTRIDE + OFF_XCONVT) + (size_t)bd*LL;
  __shared__ float tin[66*66];     // zero-padded border
  __shared__ float tout[64*65];
  const int t = threadIdx.x;
  float w9[9];
  #pragma unroll
  for(int q=0;q<9;++q) w9[q] = cw[q];
  // zero-fill (border matters; interior overwritten below after barrier)
  for(int idx=t; idx<66*66; idx+=256) tin[idx] = 0.f;
  __syncthreads();
  // vectorized interior fill: 2 x v8s per thread
  #pragma unroll
  for(int pass=0; pass<2; ++pass){
    const int e = t*8 + pass*2048;           // element index, 8-aligned
    const int row = e >> 6, col = e & 63;
    const v8s v = *(const v8s*)&xcin[e];
    #pragma unroll
    for(int q=0;q<8;++q)
      tin[(row+1)*66 + col+1 + q] = bf2f_(v[q]);
  }
  __syncthreads();
  const int w = t & 63, hb = (t>>6)*16;
  #pragma unroll
  for(int r=0;r<16;++r){
    const int h = hb + r;
    const float* tc = &tin[h*66 + w];        // (h-1+1)*66 + (w-1+1): window origin
    float acc = tc[0]*w9[0] + tc[1]*w9[1] + tc[2]*w9[2]
              + tc[66]*w9[3] + tc[67]*w9[4] + tc[68]*w9[5]
              + tc[132]*w9[6] + tc[133]*w9[7] + tc[134]*w9[8];
    const float o = silu_(acc);
    tout[h*65+w] = o;
    xconv[h*64+w] = bf16_(o);
  }
  __syncthreads();
  const int hcol = t & 63, wb = (t>>6)*16;
  #pragma unroll
  for(int r=0;r<16;++r){
    const int wp = wb + r;
    xconvT[wp*64 + hcol] = bf16_(tout[hcol*65 + wp]);
  }
}

// K3a: paired-direction x_proj from bf16 src; xdbl stored bf16.
__global__ __launch_bounds__(256) void k3a_xproj(
    const float* __restrict__ xpw_, float* __restrict__ ws)
{
  const int i = blockIdx.z;
  const int b = blockIdx.y >> 1;
  const int kp = blockIdx.y & 1;
  const int l = blockIdx.x*256 + threadIdx.x;   // source index
  const short* src = (const short*)(ws + (size_t)i*ISTRIDE + (kp? OFF_XCONVT : OFF_XCONV))
                     + (size_t)b*DI*LL;
  const float* xpwF = xpw_ + i*KK*6*DI + kp*6*DI;
  const float* xpwB = xpw_ + i*KK*6*DI + (kp+2)*6*DI;
  float accF[6] = {0,0,0,0,0,0};
  float accB[6] = {0,0,0,0,0,0};
  for(int d=0; d<DI; ++d){
    const float xv = bf2f_(src[(size_t)d*LL + l]);
    #pragma unroll
    for(int c=0;c<6;++c){
      accF[c] += xv * xpwF[c*DI + d];
      accB[c] += xv * xpwB[c*DI + d];
    }
  }
  short* xdF = (short*)(ws + (size_t)i*ISTRIDE + OFF_XDBL) + (size_t)(b*KK+kp  )*6*LL;
  short* xdB = (short*)(ws + (size_t)i*ISTRIDE + OFF_XDBL) + (size_t)(b*KK+kp+2)*6*LL;
  #pragma unroll
  for(int c=0;c<6;++c) xdF[(size_t)c*LL + l] = bf16_(accF[c]);
  #pragma unroll
  for(int c=0;c<6;++c) xdB[(size_t)c*LL + (LL-1-l)] = bf16_(accB[c]);
}

// K3b (merged): one block per (b,d); computes BOTH direction pairs (kp=0,1),
// combines y + transpose(yT) in an LDS fp32 tile, writes d-major bf16 ycombT.
// exp2-domain softplus; scan in t-units, ln2 folded at the C-multiply.
// launch_bounds (256,3): MEASURED-BEST config, bracketed across 6 variants:
// THIS FORM 49-51us; 512x8 56.3 (ILP loss > TLP gain); plain softplus 58.6;
// F/B phase-split 62.6; fp32-xdbl 73.6; (256,6) spills 110. ILP (16 loads in
// flight, interleaved F/B) is what hides latency here. Do not restructure.
__global__ __launch_bounds__(256,3) void k3b_scan(
    const float* __restrict__ dtw_, const float* __restrict__ dtb_,
    const float* __restrict__ alog_, const float* __restrict__ Ds_,
    float* __restrict__ ws)
{
  const int gid = blockIdx.x;           // b*128 + d
  const int i = blockIdx.y;
  const int d  = gid & (DI-1);
  const int b  = gid >> 7;
  const int t = threadIdx.x, lane = t & 63, wv = t >> 6;
  float* base = ws + (size_t)i*ISTRIDE;
  const int l0 = t*16;
  const int s0 = LL - 16 - l0;

  __shared__ float tile[64*65];
  __shared__ float wAg[4], wBg[4], vAg[4], vBg[4];

  #pragma unroll 1
  for(int kp=0; kp<2; ++kp){
    const short* src = (const short*)(base + (kp? OFF_XCONVT : OFF_XCONV)) + (size_t)(b*DI+d)*LL;
    const short* xdF = (const short*)(base + OFF_XDBL) + (size_t)(b*KK+kp  )*6*LL;
    const short* xdB = (const short*)(base + OFF_XDBL) + (size_t)(b*KK+kp+2)*6*LL;
    const int kdF = kp*DI + d, kdB = (kp+2)*DI + d;
    const float4 wF = ((const float4*)dtw_)[i*KK*DI + kdF];
    const float4 wB = ((const float4*)dtw_)[i*KK*DI + kdB];
    const float biasF = dtb_[i*KK*DI + kdF], biasB = dtb_[i*KK*DI + kdB];
    const float AvF = -fexp_(alog_[i*KK*DI + kdF]);
    const float AvB = -fexp_(alog_[i*KK*DI + kdB]);
    const float Dsum = Ds_[i*KK*DI + kdF] + Ds_[i*KK*DI + kdB];

    float vX[16], aF[16], bF[16], aB[16], bB[16];
    float fA = 1.f, fB = 0.f, gA = 1.f, gB = 0.f;
    LD16H(vX, src + l0);

    {
      float pre[16], r0[16];
      LD16H(r0, xdF + 0*LL + l0);
      #pragma unroll
      for(int j=0;j<16;++j) pre[j] = biasF + wF.x*r0[j];
      LD16H(r0, xdF + 1*LL + l0);
      #pragma unroll
      for(int j=0;j<16;++j) pre[j] += wF.y*r0[j];
      LD16H(r0, xdF + 2*LL + l0);
      #pragma unroll
      for(int j=0;j<16;++j) pre[j] += wF.z*r0[j];
      LD16H(r0, xdF + 3*LL + l0);
      #pragma unroll
      for(int j=0;j<16;++j) pre[j] += wF.w*r0[j];
      LD16H(r0, xdF + 4*LL + l0);   // Bs
      #pragma unroll
      for(int j=0;j<16;++j){
        const float tt = __builtin_log2f(1.f + __builtin_exp2f(pre[j]*LOG2E));
        aF[j] = __builtin_exp2f(AvF*tt);
        bF[j] = tt*r0[j]*vX[j];
        fB = fB*aF[j] + bF[j];
        fA *= aF[j];
      }
    }
    {
      float pre[16], r0[16];
      LD16HR(r0, xdB + 0*LL + s0);
      #pragma unroll
      for(int j=0;j<16;++j) pre[j] = biasB + wB.x*r0[j];
      LD16HR(r0, xdB + 1*LL + s0);
      #pragma unroll
      for(int j=0;j<16;++j) pre[j] += wB.y*r0[j];
      LD16HR(r0, xdB + 2*LL + s0);
      #pragma unroll
      for(int j=0;j<16;++j) pre[j] += wB.z*r0[j];
      LD16HR(r0, xdB + 3*LL + s0);
      #pragma unroll
      for(int j=0;j<16;++j) pre[j] += wB.w*r0[j];
      LD16HR(r0, xdB + 4*LL + s0);  // Bs reversed
      #pragma unroll
      for(int j=15;j>=0;--j){
        const float tt = __builtin_log2f(1.f + __builtin_exp2f(pre[j]*LOG2E));
        aB[j] = __builtin_exp2f(AvB*tt);
        bB[j] = tt*r0[j]*vX[j];
        gB = gB*aB[j] + bB[j];
        gA *= aB[j];
      }
    }

    #pragma unroll
    for(int off=1; off<64; off<<=1){
      const float aL = __shfl_up(fA, off);
      const float bL = __shfl_up(fB, off);
      if(lane >= off){ fB = bL*fA + fB; fA = aL*fA; }
    }
    float pA = __shfl_up(fA, 1), pB = __shfl_up(fB, 1);
    if(lane==0){ pA=1.f; pB=0.f; }
    #pragma unroll
    for(int off=1; off<64; off<<=1){
      const float aR = __shfl_down(gA, off);
      const float bR = __shfl_down(gB, off);
      if(lane + off < 64){ gB = gA*bR + gB; gA = gA*aR; }
    }
    float qA = __shfl_down(gA, 1), qB = __shfl_down(gB, 1);
    if(lane==63){ qA=1.f; qB=0.f; }

    if(kp) __syncthreads();
    if(lane==63){ wAg[wv]=fA; wBg[wv]=fB; }
    if(lane==0){ vAg[wv]=gA; vBg[wv]=gB; }
    __syncthreads();
    float eB=0.f;
    for(int u=0; u<wv; ++u){ eB = wAg[u]*eB + wBg[u]; }
    float rB=0.f;
    for(int u=3; u>wv; --u){ rB = vAg[u]*rB + vBg[u]; }

    float hf = pA*eB + pB;
    float hb = qA*rB + qB;

    float out[16], cc[16];
    LD16H(cc, xdF + 5*LL + l0);
    #pragma unroll
    for(int j=0;j<16;++j){
      hf = aF[j]*hf + bF[j];
      out[j] = hf*(cc[j]*LN2F) + Dsum*vX[j];   // ln2 fold (scan in t-units)
    }
    LD16HR(cc, xdB + 5*LL + s0);
    #pragma unroll
    for(int j=15;j>=0;--j){
      hb = aB[j]*hb + bB[j];
      out[j] += hb*(cc[j]*LN2F);
    }

    if(kp==0){
      #pragma unroll
      for(int j=0;j<16;++j){
        const int l = l0 + j;
        tile[(l>>6)*65 + (l&63)] = out[j];
      }
    } else {
      #pragma unroll
      for(int j=0;j<16;++j){
        const int q = l0 + j;
        tile[(q&63)*65 + (q>>6)] += out[j];
      }
    }
  }

  __syncthreads();
  {
    short* ycT = (short*)(base + OFF_YCOMBT);
    float o[16];
    #pragma unroll
    for(int j=0;j<16;++j)
      o[j] = tile[(t>>2)*65 + (t&3)*16 + j];
    ST16H(ycT + (size_t)d*LB + b*LL + l0, o);
  }
}

// K4a (MFMA): block = 64 pixels, 4 waves; LN via padded LDS stats (bf16 in);
// out_proj mfma (bf16 weights pre-staged); +xin -> xnew (bf16).
__global__ __launch_bounds__(256) void k4a_proj(
    const float* __restrict__ xmag, const float* __restrict__ xph,
    const float* __restrict__ onw_, const float* __restrict__ onb_,
    float* __restrict__ ws)
{
  const int i = blockIdx.y;
  const float* xin = i ? xph : xmag;
  const float* onw = onw_ + i*DI;
  const float* onb = onb_ + i*DI;
  float* base = ws + (size_t)i*ISTRIDE;
  const short* ycT = (const short*)(base + OFF_YCOMBT);
  const short* zT  = (const short*)(base + OFF_Z);
  const short* wb  = (const short*)(base + OFF_WB);
  const int t = threadIdx.x, lane = t & 63;
  const int wv = __builtin_amdgcn_readfirstlane(t >> 6);
  const int m = lane & 15, quad = lane >> 4;
  const int p0 = blockIdx.x*64;
  const int p = p0 + lane;

  __shared__ short ynlds[64*136];
  __shared__ short wlds[64*136];
  __shared__ float st[64][9];

  float yv[32];
  float s1=0.f, s2=0.f;
  #pragma unroll 8
  for(int c=0;c<32;++c){
    const float v = bf2f_(ycT[(size_t)(wv*32+c)*LB + p]);
    yv[c]=v; s1+=v; s2+=v*v;
  }
  st[lane][wv*2]=s1; st[lane][wv*2+1]=s2;
  __syncthreads();
  const float S1 = st[lane][0]+st[lane][2]+st[lane][4]+st[lane][6];
  const float S2 = st[lane][1]+st[lane][3]+st[lane][5]+st[lane][7];
  const float mu = S1*(1.f/DI);
  const float rs = rsqrtf(S2*(1.f/DI) - mu*mu + EPSF);
  #pragma unroll
  for(int cq=0;cq<8;++cq){
    short4 s4;
    #pragma unroll
    for(int e=0;e<4;++e){
      const int c = cq*4+e;
      const int d = wv*32 + c;
      ((short*)&s4)[e] = bf16_(((yv[c]-mu)*rs*onw[d] + onb[d]) * bf2f_(zT[(size_t)d*LB + p]));
    }
    *(short4*)&ynlds[lane*136 + wv*32 + cq*4] = s4;
  }
  {
    const int ol = t >> 2, seg = (t & 3)*32;
    const short* src = wb + WB_OPW + (size_t)ol*DI + seg;
    #pragma unroll
    for(int q=0;q<4;++q)
      *(v8s*)&wlds[ol*136 + seg + q*8] = ((const v8s*)src)[q];
  }
  __syncthreads();

  v4f accs[4];
  #pragma unroll
  for(int nt=0; nt<4; ++nt){
    v4f acc = (v4f){0.f,0.f,0.f,0.f};
    #pragma unroll
    for(int ks=0; ks<4; ++ks){
      const v8s a = *(const v8s*)&ynlds[(wv*16 + m)*136 + ks*32 + quad*8];
      const v8s b = *(const v8s*)&wlds[(nt*16 + m)*136 + ks*32 + quad*8];
      acc = __builtin_amdgcn_mfma_f32_16x16x32_bf16(a, b, acc, 0, 0, 0);
    }
    accs[nt] = acc;
  }
  short* xnew = (short*)(base + OFF_XNEW);
  #pragma unroll
  for(int nt=0; nt<4; ++nt){
    #pragma unroll
    for(int r=0;r<4;++r){
      const int pp = p0 + wv*16 + quad*4 + r;
      const int o = nt*16 + m;
      xnew[(size_t)pp*CC + o] = bf16_(accs[nt][r] + xin[(size_t)pp*CC + o]);
    }
  }
}

// K4b (MFMA, fused k5): 64-pixel tile, 4 waves; loops both instances in-block.
// LN2 distributed across ALL threads (pixel t>>2, channels (t&3)*16; quad
// shfl_xor reduce) -- removes the old 4x-redundant per-wave load+stats.
// Accumulates fc2+bias+residual in fp32 regs; writes both output halves.
__global__ __launch_bounds__(256) void k4b_mlp(
    const float* __restrict__ n2w_, const float* __restrict__ n2b_,
    const float* __restrict__ f1b_, const float* __restrict__ f2b_,
    float* __restrict__ ws, float* __restrict__ out)
{
  const int t = threadIdx.x, lane = t & 63;
  const int wv = __builtin_amdgcn_readfirstlane(t >> 6);
  const int m = lane & 15, quad = lane >> 4;
  const int p0 = blockIdx.x*64;

  __shared__ short hlds[64*72];
  __shared__ short w1lds[128*72];
  __shared__ short glds[64*136];
  __shared__ short w2lds[64*136];

  float outsum[16];
  #pragma unroll
  for(int e=0;e<16;++e) outsum[e]=0.f;

  #pragma unroll 1
  for(int i=0;i<2;++i){
    float* base = ws + (size_t)i*ISTRIDE;
    const short* xnew = (const short*)(base + OFF_XNEW);
    const short* wb   = (const short*)(base + OFF_WB);
    const float* n2w = n2w_ + i*CC;
    const float* n2b = n2b_ + i*CC;
    const float* f1b = f1b_ + i*256;
    const float* f2b = f2b_ + i*CC;

    if(i) __syncthreads();   // protect LDS reuse across instances

    {
      const int pix = t >> 2, seg = (t & 3)*16;
      float h2[16];
      LD16H(h2, xnew + (size_t)(p0 + pix)*CC + seg);
      float s1=0.f, s2=0.f;
      #pragma unroll
      for(int c=0;c<16;++c){ s1 += h2[c]; s2 += h2[c]*h2[c]; }
      s1 += __shfl_xor(s1, 1); s2 += __shfl_xor(s2, 1);
      s1 += __shfl_xor(s1, 2); s2 += __shfl_xor(s2, 2);
      const float mu = s1*(1.f/CC);
      const float rs = rsqrtf(s2*(1.f/CC) - mu*mu + EPSF);
      v8s o0, o1;
      #pragma unroll
      for(int e=0;e<8;++e){
        o0[e] = bf16_((h2[e]  -mu)*rs*n2w[seg+e]   + n2b[seg+e]);
        o1[e] = bf16_((h2[8+e]-mu)*rs*n2w[seg+8+e] + n2b[seg+8+e]);
      }
      *(v8s*)&hlds[pix*72 + seg]     = o0;
      *(v8s*)&hlds[pix*72 + seg + 8] = o1;
    }

    v4f acc2[4];
    #pragma unroll
    for(int n=0;n<4;++n) acc2[n] = (v4f){0.f,0.f,0.f,0.f};

    for(int h=0; h<2; ++h){
      if(h) __syncthreads();
      {
        const int jl = t >> 1, hc = (t & 1)*32;
        const short* src = wb + WB_F1W + (size_t)(h*128 + jl)*64 + hc;
        #pragma unroll
        for(int q=0;q<4;++q)
          *(v8s*)&w1lds[jl*72 + hc + q*8] = ((const v8s*)src)[q];
      }
      {
        const int ol = t >> 2, seg = (t & 3)*32;
        const short* src = wb + WB_F2W + (size_t)ol*256 + h*128 + seg;
        #pragma unroll
        for(int q=0;q<4;++q)
          *(v8s*)&w2lds[ol*136 + seg + q*8] = ((const v8s*)src)[q];
      }
      __syncthreads();
      #pragma unroll 2
      for(int nt=0; nt<8; ++nt){
        v4f acc = (v4f){0.f,0.f,0.f,0.f};
        #pragma unroll
        for(int ks=0; ks<2; ++ks){
          const v8s a = *(const v8s*)&hlds[(wv*16 + m)*72 + ks*32 + quad*8];
          const v8s b = *(const v8s*)&w1lds[(nt*16 + m)*72 + ks*32 + quad*8];
          acc = __builtin_amdgcn_mfma_f32_16x16x32_bf16(a, b, acc, 0, 0, 0);
        }
        const float bj = f1b[h*128 + nt*16 + m];
        #pragma unroll
        for(int r=0;r<4;++r){
          glds[(wv*16 + quad*4 + r)*136 + nt*16 + m] = bf16_(geluf_(acc[r] + bj));
        }
      }
      #pragma unroll
      for(int nt=0; nt<4; ++nt){
        v4f acc = acc2[nt];
        #pragma unroll
        for(int ks=0; ks<4; ++ks){
          const v8s a = *(const v8s*)&glds[(wv*16 + m)*136 + ks*32 + quad*8];
          const v8s b = *(const v8s*)&w2lds[(nt*16 + m)*136 + ks*32 + quad*8];
          acc = __builtin_amdgcn_mfma_f32_16x16x32_bf16(a, b, acc, 0, 0, 0);
        }
        acc2[nt] = acc;
      }
    }

    #pragma unroll
    for(int nt=0; nt<4; ++nt){
      const float bo = f2b[nt*16 + m];
      #pragma unroll
      for(int r=0;r<4;++r){
        const int pp = p0 + wv*16 + quad*4 + r;
        const int o  = nt*16 + m;
        outsum[nt*4+r] += acc2[nt][r] + bo + bf2f_(xnew[(size_t)pp*CC + o]);
      }
    }
  }

  #pragma unroll
  for(int nt=0; nt<4; ++nt){
    #pragma unroll
    for(int r=0;r<4;++r){
      const int pp = p0 + wv*16 + quad*4 + r;
      const int o  = nt*16 + m;
      out[(size_t)pp*CC + o] = outsum[nt*4+r];
      out[(size_t)NPIX + (size_t)pp*CC + o] = outsum[nt*4+r];
    }
  }
}

extern "C" void kernel_launch(void* const* d_in, const int* in_sizes, int n_in,
                              void* d_out, int out_size, void* d_ws, size_t ws_size,
                              hipStream_t stream)
{
  const float* mag  = (const float*)d_in[0];
  const float* ph   = (const float*)d_in[1];
  const float* n1w  = (const float*)d_in[2];
  const float* n1b  = (const float*)d_in[3];
  const float* ipw  = (const float*)d_in[4];
  const float* cw   = (const float*)d_in[5];
  const float* xpw  = (const float*)d_in[6];
  const float* dtw  = (const float*)d_in[7];
  const float* dtb  = (const float*)d_in[8];
  const float* alog = (const float*)d_in[9];
  const float* Ds   = (const float*)d_in[10];
  const float* onw  = (const float*)d_in[11];
  const float* onb  = (const float*)d_in[12];
  const float* opw  = (const float*)d_in[13];
  const float* n2w  = (const float*)d_in[14];
  const float* n2b  = (const float*)d_in[15];
  const float* f1w  = (const float*)d_in[16];
  const float* f1b  = (const float*)d_in[17];
  const float* f2w  = (const float*)d_in[18];
  const float* f2b  = (const float*)d_in[19];
  float* ws = (float*)d_ws;
  float* out = (float*)d_out;

  kw_prep     <<<dim3(56,2),   256, 0, stream>>>(ipw, opw, f1w, f2w, ws);
  k1_ln_inproj<<<dim3(512,2),  256, 0, stream>>>(mag, ph, n1w, n1b, ws);
  k2_dwconv   <<<dim3(1024,2), 256, 0, stream>>>(cw, ws);
  k3a_xproj   <<<dim3(16,16,2),256, 0, stream>>>(xpw, ws);
  k3b_scan    <<<dim3(1024,2), 256, 0, stream>>>(dtw, dtb, alog, Ds, ws);
  k4a_proj    <<<dim3(512,2),  256, 0, stream>>>(mag, ph, onw, onb, ws);
  k4b_mlp     <<<dim3(512),    256, 0, stream>>>(n2w, n2b, f1b, f2b, ws, out);
}

// Round 19
// 246.043 us; speedup vs baseline: 1.0488x; 1.0002x over previous
//
#include <hip/hip_runtime.h>
#include <math.h>

// Problem constants
#define LL   4096      // H*W
#define DI   128       // 2*C
#define CC   64        // C
#define BB   8         // batch
#define KK   4         // scan directions
#define LB   32768     // pixels per instance
#define NPIX 2097152   // B*H*W*C elements of s
#define EPSF 1e-5f
#define LOG2E 1.44269504089f
#define LN2F  0.69314718056f

// Workspace layout (float-indexed offsets; most regions hold bf16).
#define OFF_XCIN   ((size_t)0)
#define OFF_XCONV  ((size_t)4194304)
#define OFF_XCONVT ((size_t)8388608)
#define OFF_Z      ((size_t)12582912)
#define OFF_Y      ((size_t)16777216)
#define OFF_YT     ((size_t)20971520)
#define OFF_XDBL   ((size_t)25165824)   // bf16: 786432 shorts (lower half of region)
#define ISTRIDE    ((size_t)25952256)   // floats per instance
// Aliases (lifetime-disjoint reuse):
#define OFF_YCOMBT OFF_XCIN             // xcin dead after k2; ycombT (d-major) by k3b
#define OFF_XNEW   OFF_YT               // xnew (pixel-major bf16) by k4a
// bf16 weight block: dead upper part of the OFF_Y region.
#define OFF_WB     (OFF_Y + (size_t)2097152)
// short-offsets inside the weight block:
#define WB_IPW 0        // [256][64]
#define WB_OPW 16384    // [64][128]
#define WB_F1W 24576    // [256][64]
#define WB_F2W 40960    // [64][256]
#define WB_TOT 57344

typedef short v8s __attribute__((ext_vector_type(8)));
typedef float v4f __attribute__((ext_vector_type(4)));

__device__ __forceinline__ float fexp_(float x){ return __expf(x); }
__device__ __forceinline__ float silu_(float x){ return __fdividef(x, 1.f+__expf(-x)); }
__device__ __forceinline__ float geluf_(float x){ return 0.5f*x*(1.f+erff(x*0.70710678118f)); }
__device__ __forceinline__ short bf16_(float x){
  unsigned u = __float_as_uint(x);
  u += 0x7FFF + ((u>>16)&1);     // RNE
  return (short)(u>>16);
}
__device__ __forceinline__ float bf2f_(short s){
  return __uint_as_float(((unsigned)(unsigned short)s)<<16);
}

#define LD16(dst, ptr) { const float4* p4_=(const float4*)(ptr);                 \
  float4 v0_=p4_[0], v1_=p4_[1], v2_=p4_[2], v3_=p4_[3];                         \
  dst[0]=v0_.x; dst[1]=v0_.y; dst[2]=v0_.z; dst[3]=v0_.w;                        \
  dst[4]=v1_.x; dst[5]=v1_.y; dst[6]=v1_.z; dst[7]=v1_.w;                        \
  dst[8]=v2_.x; dst[9]=v2_.y; dst[10]=v2_.z; dst[11]=v2_.w;                      \
  dst[12]=v3_.x; dst[13]=v3_.y; dst[14]=v3_.z; dst[15]=v3_.w; }
// 16 bf16 (32B) -> 16 floats
#define LD16H(dst, ptr) { const v8s* p8_=(const v8s*)(ptr);                      \
  v8s a0_=p8_[0], a1_=p8_[1];                                                    \
  _Pragma("unroll") for(int e_=0;e_<8;++e_){ dst[e_]=bf2f_(a0_[e_]);             \
                                             dst[8+e_]=bf2f_(a1_[e_]); } }
// 16 bf16 reversed: dst[15-m] = ptr[m]
#define LD16HR(dst, ptr) { const v8s* p8_=(const v8s*)(ptr);                     \
  v8s a0_=p8_[0], a1_=p8_[1];                                                    \
  _Pragma("unroll") for(int e_=0;e_<8;++e_){ dst[15-e_]=bf2f_(a0_[e_]);          \
                                             dst[7-e_]=bf2f_(a1_[e_]); } }
// 16 floats -> 16 bf16 (2 v8s stores)
#define ST16H(ptr, srcv) { v8s o0_, o1_;                                         \
  _Pragma("unroll") for(int e_=0;e_<8;++e_){ o0_[e_]=bf16_(srcv[e_]);            \
                                             o1_[e_]=bf16_(srcv[8+e_]); }        \
  ((v8s*)(ptr))[0]=o0_; ((v8s*)(ptr))[1]=o1_; }

// KW: one-shot f32 -> bf16 conversion of all MFMA weight matrices into ws.
__global__ __launch_bounds__(256) void kw_prep(
    const float* __restrict__ ipw_, const float* __restrict__ opw_,
    const float* __restrict__ f1w_, const float* __restrict__ f2w_,
    float* __restrict__ ws)
{
  const int i = blockIdx.y;
  short* wb = (short*)(ws + (size_t)i*ISTRIDE + OFF_WB);
  const int e0 = blockIdx.x*1024 + threadIdx.x;
  #pragma unroll
  for(int k=0;k<4;++k){
    const int e = e0 + k*256;
    float v;
    if(e < WB_OPW)      v = ipw_[(size_t)i*16384 + e];
    else if(e < WB_F1W) v = opw_[(size_t)i*8192  + (e - WB_OPW)];
    else if(e < WB_F2W) v = f1w_[(size_t)i*16384 + (e - WB_F1W)];
    else                v = f2w_[(size_t)i*16384 + (e - WB_F2W)];
    wb[e] = bf16_(v);
  }
}

// K1 (MFMA): block = 64 pixels, 4 waves; LN distributed across ALL threads
// (thread t owns pixel t>>2, channels (t&3)*16..+16; quad shfl_xor reduce) --
// removes the old 4x-redundant per-wave load+stats. ipw staged per half from
// pre-converted bf16 weights; outputs xcin (bf16, b,d,l) and zT (bf16 silu).
__global__ __launch_bounds__(256) void k1_ln_inproj(
    const float* __restrict__ xmag, const float* __restrict__ xph,
    const float* __restrict__ n1w_, const float* __restrict__ n1b_,
    float* __restrict__ ws)
{
  const int i = blockIdx.y;
  const float* xin = i ? xph : xmag;
  const float* n1w = n1w_ + i*CC;
  const float* n1b = n1b_ + i*CC;
  float* base = ws + (size_t)i*ISTRIDE;
  const short* wb_ipw = (const short*)(base + OFF_WB) + WB_IPW;
  const int t = threadIdx.x, lane = t & 63;
  const int wv = __builtin_amdgcn_readfirstlane(t >> 6);
  const int m = lane & 15, quad = lane >> 4;
  const int p0 = blockIdx.x*64;
  const int b = p0 >> 12, l0 = p0 & (LL-1);

  __shared__ short hlds[64*72];
  __shared__ short w1lds[128*72];
  __shared__ float outs[128*68];

  {
    const int pix = t >> 2, seg = (t & 3)*16;
    float hn[16];
    LD16(hn, xin + (size_t)(p0 + pix)*CC + seg);
    float s1=0.f, s2=0.f;
    #pragma unroll
    for(int c=0;c<16;++c){ s1 += hn[c]; s2 += hn[c]*hn[c]; }
    s1 += __shfl_xor(s1, 1); s2 += __shfl_xor(s2, 1);
    s1 += __shfl_xor(s1, 2); s2 += __shfl_xor(s2, 2);
    const float mu = s1*(1.f/CC);
    const float rs = rsqrtf(s2*(1.f/CC) - mu*mu + EPSF);
    v8s o0, o1;
    #pragma unroll
    for(int e=0;e<8;++e){
      o0[e] = bf16_((hn[e]  -mu)*rs*n1w[seg+e]   + n1b[seg+e]);
      o1[e] = bf16_((hn[8+e]-mu)*rs*n1w[seg+8+e] + n1b[seg+8+e]);
    }
    *(v8s*)&hlds[pix*72 + seg]     = o0;
    *(v8s*)&hlds[pix*72 + seg + 8] = o1;
  }

  for(int h=0; h<2; ++h){
    if(h) __syncthreads();
    {
      const int jl = t >> 1, hc = (t & 1)*32;
      const short* src = wb_ipw + (size_t)(h*128 + jl)*64 + hc;
      #pragma unroll
      for(int q=0;q<4;++q)
        *(v8s*)&w1lds[jl*72 + hc + q*8] = ((const v8s*)src)[q];
    }
    __syncthreads();
    #pragma unroll 2
    for(int nt=0; nt<8; ++nt){
      v4f acc = (v4f){0.f,0.f,0.f,0.f};
      #pragma unroll
      for(int ks=0; ks<2; ++ks){
        const v8s a = *(const v8s*)&hlds[(wv*16 + m)*72 + ks*32 + quad*8];
        const v8s bb = *(const v8s*)&w1lds[(nt*16 + m)*72 + ks*32 + quad*8];
        acc = __builtin_amdgcn_mfma_f32_16x16x32_bf16(a, bb, acc, 0, 0, 0);
      }
      *(float4*)&outs[(nt*16 + m)*68 + wv*16 + quad*4] =
          make_float4(acc[0], acc[1], acc[2], acc[3]);
    }
    __syncthreads();
    const int jl = t >> 1, hc = (t & 1)*32;
    if(h==0){
      short* xcb = (short*)(base + OFF_XCIN) + (size_t)b*DI*LL + (size_t)jl*LL + l0 + hc;
      const float* so = &outs[jl*68 + hc];
      ST16H(xcb, so);
      ST16H(xcb+16, (so+16));
    } else {
      short* zr = (short*)(base + OFF_Z) + (size_t)jl*LB + p0 + hc;
      float tmp[32];
      #pragma unroll
      for(int e=0;e<32;++e) tmp[e] = silu_(outs[jl*68 + hc + e]);
      ST16H(zr, tmp);
      ST16H(zr+16, (tmp+16));
    }
  }
}

// K2: depthwise 3x3 conv + silu; bf16 in (xcin), bf16 out (xconv/xconvT).
// v8s-vectorized input load into a zero-padded 66x66 fp32 tile -> branch-free
// 3x3 window (no bounds checks).
__global__ __launch_bounds__(256) void k2_dwconv(
    const float* __restrict__ cw_, float* __restrict__ ws)
{
  const int i = blockIdx.y;
  const int bd = blockIdx.x;
  const int d = bd & (DI-1);
  const float* cw = cw_ + i*DI*9 + d*9;
  const short* xcin = (const short*)(ws + (size_t)i*ISTRIDE + OFF_XCIN) + (size_t)bd*LL;
  short* xconv  = (short*)(ws + (size_t)i*ISTRIDE + OFF_XCONV ) + (size_t)bd*LL;
  short* xconvT = (short*)(ws + (size_t)i*ISTRIDE + OFF_XCONVT) + (size_t)bd*LL;
  __shared__ float tin[66*66];     // zero-padded border
  __shared__ float tout[64*65];
  const int t = threadIdx.x;
  float w9[9];
  #pragma unroll
  for(int q=0;q<9;++q) w9[q] = cw[q];
  // zero-fill (border matters; interior overwritten below after barrier)
  for(int idx=t; idx<66*66; idx+=256) tin[idx] = 0.f;
  __syncthreads();
  // vectorized interior fill: 2 x v8s per thread
  #pragma unroll
  for(int pass=0; pass<2; ++pass){
    const int e = t*8 + pass*2048;           // element index, 8-aligned
    const int row = e >> 6, col = e & 63;
    const v8s v = *(const v8s*)&xcin[e];
    #pragma unroll
    for(int q=0;q<8;++q)
      tin[(row+1)*66 + col+1 + q] = bf2f_(v[q]);
  }
  __syncthreads();
  const int w = t & 63, hb = (t>>6)*16;
  #pragma unroll
  for(int r=0;r<16;++r){
    const int h = hb + r;
    const float* tc = &tin[h*66 + w];        // window origin
    float acc = tc[0]*w9[0] + tc[1]*w9[1] + tc[2]*w9[2]
              + tc[66]*w9[3] + tc[67]*w9[4] + tc[68]*w9[5]
              + tc[132]*w9[6] + tc[133]*w9[7] + tc[134]*w9[8];
    const float o = silu_(acc);
    tout[h*65+w] = o;
    xconv[h*64+w] = bf16_(o);
  }
  __syncthreads();
  const int hcol = t & 63, wb = (t>>6)*16;
  #pragma unroll
  for(int r=0;r<16;++r){
    const int wp = wb + r;
    xconvT[wp*64 + hcol] = bf16_(tout[hcol*65 + wp]);
  }
}

// K3a: paired-direction x_proj from bf16 src; xdbl stored bf16.
__global__ __launch_bounds__(256) void k3a_xproj(
    const float* __restrict__ xpw_, float* __restrict__ ws)
{
  const int i = blockIdx.z;
  const int b = blockIdx.y >> 1;
  const int kp = blockIdx.y & 1;
  const int l = blockIdx.x*256 + threadIdx.x;   // source index
  const short* src = (const short*)(ws + (size_t)i*ISTRIDE + (kp? OFF_XCONVT : OFF_XCONV))
                     + (size_t)b*DI*LL;
  const float* xpwF = xpw_ + i*KK*6*DI + kp*6*DI;
  const float* xpwB = xpw_ + i*KK*6*DI + (kp+2)*6*DI;
  float accF[6] = {0,0,0,0,0,0};
  float accB[6] = {0,0,0,0,0,0};
  for(int d=0; d<DI; ++d){
    const float xv = bf2f_(src[(size_t)d*LL + l]);
    #pragma unroll
    for(int c=0;c<6;++c){
      accF[c] += xv * xpwF[c*DI + d];
      accB[c] += xv * xpwB[c*DI + d];
    }
  }
  short* xdF = (short*)(ws + (size_t)i*ISTRIDE + OFF_XDBL) + (size_t)(b*KK+kp  )*6*LL;
  short* xdB = (short*)(ws + (size_t)i*ISTRIDE + OFF_XDBL) + (size_t)(b*KK+kp+2)*6*LL;
  #pragma unroll
  for(int c=0;c<6;++c) xdF[(size_t)c*LL + l] = bf16_(accF[c]);
  #pragma unroll
  for(int c=0;c<6;++c) xdB[(size_t)c*LL + (LL-1-l)] = bf16_(accB[c]);
}

// K3b (merged): one block per (b,d); computes BOTH direction pairs (kp=0,1),
// combines y + transpose(yT) in an LDS fp32 tile, writes d-major bf16 ycombT.
// exp2-domain softplus; scan in t-units, ln2 folded at the C-multiply.
// launch_bounds (256,3): MEASURED-BEST config, bracketed across 6 variants:
// THIS FORM 49-64us (run-to-run band at fixed code); 512x8 56.3; plain
// softplus 58.6; F/B phase-split 62.6; fp32-xdbl 73.6; (256,6) spills 110.
// ILP (16 loads in flight, interleaved F/B) hides latency. Do not restructure.
__global__ __launch_bounds__(256,3) void k3b_scan(
    const float* __restrict__ dtw_, const float* __restrict__ dtb_,
    const float* __restrict__ alog_, const float* __restrict__ Ds_,
    float* __restrict__ ws)
{
  const int gid = blockIdx.x;           // b*128 + d
  const int i = blockIdx.y;
  const int d  = gid & (DI-1);
  const int b  = gid >> 7;
  const int t = threadIdx.x, lane = t & 63, wv = t >> 6;
  float* base = ws + (size_t)i*ISTRIDE;
  const int l0 = t*16;
  const int s0 = LL - 16 - l0;

  __shared__ float tile[64*65];
  __shared__ float wAg[4], wBg[4], vAg[4], vBg[4];

  #pragma unroll 1
  for(int kp=0; kp<2; ++kp){
    const short* src = (const short*)(base + (kp? OFF_XCONVT : OFF_XCONV)) + (size_t)(b*DI+d)*LL;
    const short* xdF = (const short*)(base + OFF_XDBL) + (size_t)(b*KK+kp  )*6*LL;
    const short* xdB = (const short*)(base + OFF_XDBL) + (size_t)(b*KK+kp+2)*6*LL;
    const int kdF = kp*DI + d, kdB = (kp+2)*DI + d;
    const float4 wF = ((const float4*)dtw_)[i*KK*DI + kdF];
    const float4 wB = ((const float4*)dtw_)[i*KK*DI + kdB];
    const float biasF = dtb_[i*KK*DI + kdF], biasB = dtb_[i*KK*DI + kdB];
    const float AvF = -fexp_(alog_[i*KK*DI + kdF]);
    const float AvB = -fexp_(alog_[i*KK*DI + kdB]);
    const float Dsum = Ds_[i*KK*DI + kdF] + Ds_[i*KK*DI + kdB];

    float vX[16], aF[16], bF[16], aB[16], bB[16];
    float fA = 1.f, fB = 0.f, gA = 1.f, gB = 0.f;
    LD16H(vX, src + l0);

    {
      float pre[16], r0[16];
      LD16H(r0, xdF + 0*LL + l0);
      #pragma unroll
      for(int j=0;j<16;++j) pre[j] = biasF + wF.x*r0[j];
      LD16H(r0, xdF + 1*LL + l0);
      #pragma unroll
      for(int j=0;j<16;++j) pre[j] += wF.y*r0[j];
      LD16H(r0, xdF + 2*LL + l0);
      #pragma unroll
      for(int j=0;j<16;++j) pre[j] += wF.z*r0[j];
      LD16H(r0, xdF + 3*LL + l0);
      #pragma unroll
      for(int j=0;j<16;++j) pre[j] += wF.w*r0[j];
      LD16H(r0, xdF + 4*LL + l0);   // Bs
      #pragma unroll
      for(int j=0;j<16;++j){
        const float tt = __builtin_log2f(1.f + __builtin_exp2f(pre[j]*LOG2E));
        aF[j] = __builtin_exp2f(AvF*tt);
        bF[j] = tt*r0[j]*vX[j];
        fB = fB*aF[j] + bF[j];
        fA *= aF[j];
      }
    }
    {
      float pre[16], r0[16];
      LD16HR(r0, xdB + 0*LL + s0);
      #pragma unroll
      for(int j=0;j<16;++j) pre[j] = biasB + wB.x*r0[j];
      LD16HR(r0, xdB + 1*LL + s0);
      #pragma unroll
      for(int j=0;j<16;++j) pre[j] += wB.y*r0[j];
      LD16HR(r0, xdB + 2*LL + s0);
      #pragma unroll
      for(int j=0;j<16;++j) pre[j] += wB.z*r0[j];
      LD16HR(r0, xdB + 3*LL + s0);
      #pragma unroll
      for(int j=0;j<16;++j) pre[j] += wB.w*r0[j];
      LD16HR(r0, xdB + 4*LL + s0);  // Bs reversed
      #pragma unroll
      for(int j=15;j>=0;--j){
        const float tt = __builtin_log2f(1.f + __builtin_exp2f(pre[j]*LOG2E));
        aB[j] = __builtin_exp2f(AvB*tt);
        bB[j] = tt*r0[j]*vX[j];
        gB = gB*aB[j] + bB[j];
        gA *= aB[j];
      }
    }

    #pragma unroll
    for(int off=1; off<64; off<<=1){
      const float aL = __shfl_up(fA, off);
      const float bL = __shfl_up(fB, off);
      if(lane >= off){ fB = bL*fA + fB; fA = aL*fA; }
    }
    float pA = __shfl_up(fA, 1), pB = __shfl_up(fB, 1);
    if(lane==0){ pA=1.f; pB=0.f; }
    #pragma unroll
    for(int off=1; off<64; off<<=1){
      const float aR = __shfl_down(gA, off);
      const float bR = __shfl_down(gB, off);
      if(lane + off < 64){ gB = gA*bR + gB; gA = gA*aR; }
    }
    float qA = __shfl_down(gA, 1), qB = __shfl_down(gB, 1);
    if(lane==63){ qA=1.f; qB=0.f; }

    if(kp) __syncthreads();
    if(lane==63){ wAg[wv]=fA; wBg[wv]=fB; }
    if(lane==0){ vAg[wv]=gA; vBg[wv]=gB; }
    __syncthreads();
    float eB=0.f;
    for(int u=0; u<wv; ++u){ eB = wAg[u]*eB + wBg[u]; }
    float rB=0.f;
    for(int u=3; u>wv; --u){ rB = vAg[u]*rB + vBg[u]; }

    float hf = pA*eB + pB;
    float hb = qA*rB + qB;

    float out[16], cc[16];
    LD16H(cc, xdF + 5*LL + l0);
    #pragma unroll
    for(int j=0;j<16;++j){
      hf = aF[j]*hf + bF[j];
      out[j] = hf*(cc[j]*LN2F) + Dsum*vX[j];   // ln2 fold (scan in t-units)
    }
    LD16HR(cc, xdB + 5*LL + s0);
    #pragma unroll
    for(int j=15;j>=0;--j){
      hb = aB[j]*hb + bB[j];
      out[j] += hb*(cc[j]*LN2F);
    }

    if(kp==0){
      #pragma unroll
      for(int j=0;j<16;++j){
        const int l = l0 + j;
        tile[(l>>6)*65 + (l&63)] = out[j];
      }
    } else {
      #pragma unroll
      for(int j=0;j<16;++j){
        const int q = l0 + j;
        tile[(q&63)*65 + (q>>6)] += out[j];
      }
    }
  }

  __syncthreads();
  {
    short* ycT = (short*)(base + OFF_YCOMBT);
    float o[16];
    #pragma unroll
    for(int j=0;j<16;++j)
      o[j] = tile[(t>>2)*65 + (t&3)*16 + j];
    ST16H(ycT + (size_t)d*LB + b*LL + l0, o);
  }
}

// K4a (MFMA): block = 64 pixels, 4 waves; LN via padded LDS stats (bf16 in);
// out_proj mfma (bf16 weights pre-staged); +xin -> xnew (bf16).
__global__ __launch_bounds__(256) void k4a_proj(
    const float* __restrict__ xmag, const float* __restrict__ xph,
    const float* __restrict__ onw_, const float* __restrict__ onb_,
    float* __restrict__ ws)
{
  const int i = blockIdx.y;
  const float* xin = i ? xph : xmag;
  const float* onw = onw_ + i*DI;
  const float* onb = onb_ + i*DI;
  float* base = ws + (size_t)i*ISTRIDE;
  const short* ycT = (const short*)(base + OFF_YCOMBT);
  const short* zT  = (const short*)(base + OFF_Z);
  const short* wb  = (const short*)(base + OFF_WB);
  const int t = threadIdx.x, lane = t & 63;
  const int wv = __builtin_amdgcn_readfirstlane(t >> 6);
  const int m = lane & 15, quad = lane >> 4;
  const int p0 = blockIdx.x*64;
  const int p = p0 + lane;

  __shared__ short ynlds[64*136];
  __shared__ short wlds[64*136];
  __shared__ float st[64][9];

  float yv[32];
  float s1=0.f, s2=0.f;
  #pragma unroll 8
  for(int c=0;c<32;++c){
    const float v = bf2f_(ycT[(size_t)(wv*32+c)*LB + p]);
    yv[c]=v; s1+=v; s2+=v*v;
  }
  st[lane][wv*2]=s1; st[lane][wv*2+1]=s2;
  __syncthreads();
  const float S1 = st[lane][0]+st[lane][2]+st[lane][4]+st[lane][6];
  const float S2 = st[lane][1]+st[lane][3]+st[lane][5]+st[lane][7];
  const float mu = S1*(1.f/DI);
  const float rs = rsqrtf(S2*(1.f/DI) - mu*mu + EPSF);
  #pragma unroll
  for(int cq=0;cq<8;++cq){
    short4 s4;
    #pragma unroll
    for(int e=0;e<4;++e){
      const int c = cq*4+e;
      const int d = wv*32 + c;
      ((short*)&s4)[e] = bf16_(((yv[c]-mu)*rs*onw[d] + onb[d]) * bf2f_(zT[(size_t)d*LB + p]));
    }
    *(short4*)&ynlds[lane*136 + wv*32 + cq*4] = s4;
  }
  {
    const int ol = t >> 2, seg = (t & 3)*32;
    const short* src = wb + WB_OPW + (size_t)ol*DI + seg;
    #pragma unroll
    for(int q=0;q<4;++q)
      *(v8s*)&wlds[ol*136 + seg + q*8] = ((const v8s*)src)[q];
  }
  __syncthreads();

  v4f accs[4];
  #pragma unroll
  for(int nt=0; nt<4; ++nt){
    v4f acc = (v4f){0.f,0.f,0.f,0.f};
    #pragma unroll
    for(int ks=0; ks<4; ++ks){
      const v8s a = *(const v8s*)&ynlds[(wv*16 + m)*136 + ks*32 + quad*8];
      const v8s b = *(const v8s*)&wlds[(nt*16 + m)*136 + ks*32 + quad*8];
      acc = __builtin_amdgcn_mfma_f32_16x16x32_bf16(a, b, acc, 0, 0, 0);
    }
    accs[nt] = acc;
  }
  short* xnew = (short*)(base + OFF_XNEW);
  #pragma unroll
  for(int nt=0; nt<4; ++nt){
    #pragma unroll
    for(int r=0;r<4;++r){
      const int pp = p0 + wv*16 + quad*4 + r;
      const int o = nt*16 + m;
      xnew[(size_t)pp*CC + o] = bf16_(accs[nt][r] + xin[(size_t)pp*CC + o]);
    }
  }
}

// K4b (MFMA, fused k5): 64-pixel tile, 4 waves; loops both instances in-block.
// LN2 distributed across ALL threads (pixel t>>2, channels (t&3)*16; quad
// shfl_xor reduce) -- removes the old 4x-redundant per-wave load+stats.
// Accumulates fc2+bias+residual in fp32 regs; writes both output halves.
__global__ __launch_bounds__(256) void k4b_mlp(
    const float* __restrict__ n2w_, const float* __restrict__ n2b_,
    const float* __restrict__ f1b_, const float* __restrict__ f2b_,
    float* __restrict__ ws, float* __restrict__ out)
{
  const int t = threadIdx.x, lane = t & 63;
  const int wv = __builtin_amdgcn_readfirstlane(t >> 6);
  const int m = lane & 15, quad = lane >> 4;
  const int p0 = blockIdx.x*64;

  __shared__ short hlds[64*72];
  __shared__ short w1lds[128*72];
  __shared__ short glds[64*136];
  __shared__ short w2lds[64*136];

  float outsum[16];
  #pragma unroll
  for(int e=0;e<16;++e) outsum[e]=0.f;

  #pragma unroll 1
  for(int i=0;i<2;++i){
    float* base = ws + (size_t)i*ISTRIDE;
    const short* xnew = (const short*)(base + OFF_XNEW);
    const short* wb   = (const short*)(base + OFF_WB);
    const float* n2w = n2w_ + i*CC;
    const float* n2b = n2b_ + i*CC;
    const float* f1b = f1b_ + i*256;
    const float* f2b = f2b_ + i*CC;

    if(i) __syncthreads();   // protect LDS reuse across instances

    {
      const int pix = t >> 2, seg = (t & 3)*16;
      float h2[16];
      LD16H(h2, xnew + (size_t)(p0 + pix)*CC + seg);
      float s1=0.f, s2=0.f;
      #pragma unroll
      for(int c=0;c<16;++c){ s1 += h2[c]; s2 += h2[c]*h2[c]; }
      s1 += __shfl_xor(s1, 1); s2 += __shfl_xor(s2, 1);
      s1 += __shfl_xor(s1, 2); s2 += __shfl_xor(s2, 2);
      const float mu = s1*(1.f/CC);
      const float rs = rsqrtf(s2*(1.f/CC) - mu*mu + EPSF);
      v8s o0, o1;
      #pragma unroll
      for(int e=0;e<8;++e){
        o0[e] = bf16_((h2[e]  -mu)*rs*n2w[seg+e]   + n2b[seg+e]);
        o1[e] = bf16_((h2[8+e]-mu)*rs*n2w[seg+8+e] + n2b[seg+8+e]);
      }
      *(v8s*)&hlds[pix*72 + seg]     = o0;
      *(v8s*)&hlds[pix*72 + seg + 8] = o1;
    }

    v4f acc2[4];
    #pragma unroll
    for(int n=0;n<4;++n) acc2[n] = (v4f){0.f,0.f,0.f,0.f};

    for(int h=0; h<2; ++h){
      if(h) __syncthreads();
      {
        const int jl = t >> 1, hc = (t & 1)*32;
        const short* src = wb + WB_F1W + (size_t)(h*128 + jl)*64 + hc;
        #pragma unroll
        for(int q=0;q<4;++q)
          *(v8s*)&w1lds[jl*72 + hc + q*8] = ((const v8s*)src)[q];
      }
      {
        const int ol = t >> 2, seg = (t & 3)*32;
        const short* src = wb + WB_F2W + (size_t)ol*256 + h*128 + seg;
        #pragma unroll
        for(int q=0;q<4;++q)
          *(v8s*)&w2lds[ol*136 + seg + q*8] = ((const v8s*)src)[q];
      }
      __syncthreads();
      #pragma unroll 2
      for(int nt=0; nt<8; ++nt){
        v4f acc = (v4f){0.f,0.f,0.f,0.f};
        #pragma unroll
        for(int ks=0; ks<2; ++ks){
          const v8s a = *(const v8s*)&hlds[(wv*16 + m)*72 + ks*32 + quad*8];
          const v8s b = *(const v8s*)&w1lds[(nt*16 + m)*72 + ks*32 + quad*8];
          acc = __builtin_amdgcn_mfma_f32_16x16x32_bf16(a, b, acc, 0, 0, 0);
        }
        const float bj = f1b[h*128 + nt*16 + m];
        #pragma unroll
        for(int r=0;r<4;++r){
          glds[(wv*16 + quad*4 + r)*136 + nt*16 + m] = bf16_(geluf_(acc[r] + bj));
        }
      }
      #pragma unroll
      for(int nt=0; nt<4; ++nt){
        v4f acc = acc2[nt];
        #pragma unroll
        for(int ks=0; ks<4; ++ks){
          const v8s a = *(const v8s*)&glds[(wv*16 + m)*136 + ks*32 + quad*8];
          const v8s b = *(const v8s*)&w2lds[(nt*16 + m)*136 + ks*32 + quad*8];
          acc = __builtin_amdgcn_mfma_f32_16x16x32_bf16(a, b, acc, 0, 0, 0);
        }
        acc2[nt] = acc;
      }
    }

    #pragma unroll
    for(int nt=0; nt<4; ++nt){
      const float bo = f2b[nt*16 + m];
      #pragma unroll
      for(int r=0;r<4;++r){
        const int pp = p0 + wv*16 + quad*4 + r;
        const int o  = nt*16 + m;
        outsum[nt*4+r] += acc2[nt][r] + bo + bf2f_(xnew[(size_t)pp*CC + o]);
      }
    }
  }

  #pragma unroll
  for(int nt=0; nt<4; ++nt){
    #pragma unroll
    for(int r=0;r<4;++r){
      const int pp = p0 + wv*16 + quad*4 + r;
      const int o  = nt*16 + m;
      out[(size_t)pp*CC + o] = outsum[nt*4+r];
      out[(size_t)NPIX + (size_t)pp*CC + o] = outsum[nt*4+r];
    }
  }
}

extern "C" void kernel_launch(void* const* d_in, const int* in_sizes, int n_in,
                              void* d_out, int out_size, void* d_ws, size_t ws_size,
                              hipStream_t stream)
{
  const float* mag  = (const float*)d_in[0];
  const float* ph   = (const float*)d_in[1];
  const float* n1w  = (const float*)d_in[2];
  const float* n1b  = (const float*)d_in[3];
  const float* ipw  = (const float*)d_in[4];
  const float* cw   = (const float*)d_in[5];
  const float* xpw  = (const float*)d_in[6];
  const float* dtw  = (const float*)d_in[7];
  const float* dtb  = (const float*)d_in[8];
  const float* alog = (const float*)d_in[9];
  const float* Ds   = (const float*)d_in[10];
  const float* onw  = (const float*)d_in[11];
  const float* onb  = (const float*)d_in[12];
  const float* opw  = (const float*)d_in[13];
  const float* n2w  = (const float*)d_in[14];
  const float* n2b  = (const float*)d_in[15];
  const float* f1w  = (const float*)d_in[16];
  const float* f1b  = (const float*)d_in[17];
  const float* f2w  = (const float*)d_in[18];
  const float* f2b  = (const float*)d_in[19];
  float* ws = (float*)d_ws;
  float* out = (float*)d_out;

  kw_prep     <<<dim3(56,2),   256, 0, stream>>>(ipw, opw, f1w, f2w, ws);
  k1_ln_inproj<<<dim3(512,2),  256, 0, stream>>>(mag, ph, n1w, n1b, ws);
  k2_dwconv   <<<dim3(1024,2), 256, 0, stream>>>(cw, ws);
  k3a_xproj   <<<dim3(16,16,2),256, 0, stream>>>(xpw, ws);
  k3b_scan    <<<dim3(1024,2), 256, 0, stream>>>(dtw, dtb, alog, Ds, ws);
  k4a_proj    <<<dim3(512,2),  256, 0, stream>>>(mag, ph, onw, onb, ws);
  k4b_mlp     <<<dim3(512),    256, 0, stream>>>(n2w, n2b, f1b, f2b, ws, out);
}